// Round 11
// baseline (537.288 us; speedup 1.0000x reference)
//
#include <hip/hip_runtime.h>
#include <stdint.h>

#define N_EMB 8192
#define M_TOT 16384
#define DELTA 6e-3f   // top-2 gap threshold in log2-units
#define LN_EPS 1e-5f
#define SCL 0.09016994f  // 0.0625 * log2(e): logits in log2 units

typedef _Float16 f16;
typedef f16 f16x8 __attribute__((ext_vector_type(8)));
typedef f16 f16x4 __attribute__((ext_vector_type(4)));
typedef float f32x16 __attribute__((ext_vector_type(16)));
typedef unsigned uint32x4 __attribute__((ext_vector_type(4)));

// ws layout (proven >= 74MB in R2):
// [0,4MB)  kfrag ; [4MB,8MB) vfrag
// [8MB,+4) count ; [8MB+64,+64KB) list
// [8MB+128KB, +1MB) statA float4[4][16384] ; then statB int[4][16384] (256KB)
// [10MB,42MB) embd_t fp32 [256][8192]
// [42MB,74MB) pacc f16[4][16384][256]  (dead after merge; refine part reuses)
#define WS_KFRAG 0ul
#define WS_VFRAG (4ul << 20)
#define WS_COUNT (8ul << 20)
#define WS_LIST ((8ul << 20) + 64ul)
#define WS_STATA ((8ul << 20) + (128ul << 10))
#define WS_STATB ((8ul << 20) + (128ul << 10) + (1ul << 20))
#define WS_EMBDT (10ul << 20)
#define WS_PACC (42ul << 20)
#define WS_RPART (42ul << 20)

#define MFMA32(a, b, c) __builtin_amdgcn_mfma_f32_32x32x16_f16(a, b, c, 0, 0, 0)

// ---------------- prep: fragment layouts (bid<256) + fp32 transpose (bid>=256) ----
__global__ __launch_bounds__(256) void prep_kernel(const float* __restrict__ embd,
                                                   f16* __restrict__ kfrag,
                                                   f16* __restrict__ vfrag,
                                                   float* __restrict__ embd_t,
                                                   unsigned* __restrict__ count) {
  const int t = threadIdx.x;
  const int bid = blockIdx.x;
  if (bid < 256) {
    if (bid == 0 && t == 0) *count = 0u;
    __shared__ f16 tile[32][272];
    const int c = bid;
    {
      const int r = t >> 3;
      const int d0 = (t & 7) * 32;
      const float4* src = (const float4*)(embd + (size_t)(c * 32 + r) * 256 + d0);
#pragma unroll
      for (int qd = 0; qd < 8; ++qd) {
        float4 v = src[qd];
        tile[r][d0 + qd * 4 + 0] = (f16)v.x;
        tile[r][d0 + qd * 4 + 1] = (f16)v.y;
        tile[r][d0 + qd * 4 + 2] = (f16)v.z;
        tile[r][d0 + qd * 4 + 3] = (f16)v.w;
      }
    }
    __syncthreads();
#pragma unroll
    for (int i = 0; i < 4; ++i) {
      const int u = t + i * 256;
      const int kc = u >> 6;
      const int l = u & 63;
      const f16x8 pack = *(const f16x8*)&tile[l & 31][kc * 16 + ((l >> 5) & 1) * 8];
      *(f16x8*)(kfrag + (size_t)c * 8192 + (size_t)u * 8) = pack;
    }
#pragma unroll
    for (int i = 0; i < 4; ++i) {
      const int u = t + i * 256;
      const int fi = u >> 6;
      const int l = u & 63;
      const int dt = fi >> 1, ks = fi & 1;
      f16x8 pack;
#pragma unroll
      for (int j = 0; j < 8; ++j)
        pack[j] = tile[ks * 16 + ((l >> 5) & 1) * 8 + j][dt * 32 + (l & 31)];
      *(f16x8*)(vfrag + (size_t)c * 8192 + (size_t)u * 8) = pack;
    }
  } else {
    __shared__ float ftile[32][257];
    const int c = bid - 256;
    {
      const int r = t >> 3;
      const int d0 = (t & 7) * 32;
      const float4* src = (const float4*)(embd + (size_t)(c * 32 + r) * 256 + d0);
#pragma unroll
      for (int q8 = 0; q8 < 8; ++q8) {
        const float4 v = src[q8];
        ftile[r][d0 + q8 * 4 + 0] = v.x;
        ftile[r][d0 + q8 * 4 + 1] = v.y;
        ftile[r][d0 + q8 * 4 + 2] = v.z;
        ftile[r][d0 + q8 * 4 + 3] = v.w;
      }
    }
    __syncthreads();
    const int r = t & 31;
    const int dh = t >> 5;
#pragma unroll
    for (int dd = 0; dd < 32; ++dd) {
      const int d = dd * 8 + dh;
      embd_t[(size_t)d * 8192 + c * 32 + r] = ftile[r][d];
    }
  }
}

// ---------------- fused: LN + flash softmax-quantize, XCD-pinned N-split ----------
// 512 blocks x 256 thr. s = bid&3 (n-quarter; round-robin XCD dispatch pins one
// s per XCD -> 2MB frag quarter is L2-resident, drift harmless). rg = bid>>2:
// 128 rows/block = 4 qg-waves x 32 rows. All 4 waves read IDENTICAL K/V
// addresses (L1 sharing). Chunk loop is R10's proven barrier-free body.
// Partials (acc/l as f16, stats) dumped to ws; merged by merge_kernel.
// LDS: [w*16K, +16K) = wave w's Q frags (read-only after LN).
__global__ __launch_bounds__(256, 2) void fused_kernel(
    const float* __restrict__ input, const float* __restrict__ ln_w,
    const float* __restrict__ ln_b, const f16* __restrict__ kfrag,
    const f16* __restrict__ vfrag, f16* __restrict__ pacc,
    float4* __restrict__ statA, int* __restrict__ statB) {
  __shared__ __align__(16) char lds[65536];
  const int tid = threadIdx.x;
  const int lane = tid & 63;
  const int w = tid >> 6;  // q-group
  const int q = lane & 31;
  const int hi = lane >> 5;
  const int bid = blockIdx.x;
  const int s = bid & 3;       // n-quarter (XCD-pinned)
  const int rg = bid >> 2;
  const int R0 = rg * 128;

  const f16* const kfbase = kfrag + (size_t)(s * 64) * 8192 + (size_t)lane * 8;
  const f16* const vfbase = vfrag + (size_t)(s * 64) * 8192 + (size_t)lane * 8;
  const char* const qb = lds + w * 16384 + hi * 512 + q * 16;

  // ---- kA(chunk 0) prefetch: issued before LN, consumed after ----
  f16x8 kA[8];
#pragma unroll
  for (int f = 0; f < 8; ++f) kA[f] = *(const f16x8*)(kfbase + f * 512);

  // ---- LN: 128 rows in 4 groups of 32 (8 thr/row), Q frags -> region g ----
#pragma unroll
  for (int g = 0; g < 4; ++g) {
    const int r = tid >> 3;
    const int seg = tid & 7;
    const float* rowp = input + (size_t)(R0 + g * 32 + r) * 256 + seg * 32;
    float4 xv[8];
    float sm = 0.f, ssq = 0.f;
#pragma unroll
    for (int qd = 0; qd < 8; ++qd) {
      xv[qd] = ((const float4*)rowp)[qd];
      sm += xv[qd].x + xv[qd].y + xv[qd].z + xv[qd].w;
      ssq += xv[qd].x * xv[qd].x + xv[qd].y * xv[qd].y + xv[qd].z * xv[qd].z +
             xv[qd].w * xv[qd].w;
    }
    sm += __shfl_xor(sm, 1);
    sm += __shfl_xor(sm, 2);
    sm += __shfl_xor(sm, 4);
    ssq += __shfl_xor(ssq, 1);
    ssq += __shfl_xor(ssq, 2);
    ssq += __shfl_xor(ssq, 4);
    const float mean = sm * (1.f / 256.f);
    const float var = ssq * (1.f / 256.f) - mean * mean;
    const float rstd = 1.0f / sqrtf(var + LN_EPS);
#pragma unroll
    for (int qd = 0; qd < 8; ++qd) {
      const int d0 = seg * 32 + qd * 4;
      float4 w4 = *(const float4*)(ln_w + d0);
      float4 b4 = *(const float4*)(ln_b + d0);
      f16x4 hv;
      hv[0] = (f16)((((xv[qd].x - mean) * rstd) * w4.x + b4.x) * SCL);
      hv[1] = (f16)((((xv[qd].y - mean) * rstd) * w4.y + b4.y) * SCL);
      hv[2] = (f16)((((xv[qd].z - mean) * rstd) * w4.z + b4.z) * SCL);
      hv[3] = (f16)((((xv[qd].w - mean) * rstd) * w4.w + b4.w) * SCL);
      const int off = (d0 >> 4) * 1024 + ((d0 >> 3) & 1) * 512 + r * 16 + (d0 & 7) * 2;
      *(f16x4*)(lds + g * 16384 + off) = hv;
    }
  }
  __syncthreads();  // Q regions visible; no further block syncs

  f32x16 acc[8] = {};
  float m_run = 0.f, l_run = 0.f, mt1 = -3.0e38f, mt2 = -3.0e38f;
  int i1 = 0;

  for (int c = 0; c < 64; ++c) {
    const int nb = s * 2048 + c * 32;
    const f16* const kc_base = kfbase + (size_t)c * 8192;
    const f16* const vc_base = vfbase + (size_t)c * 8192;
    // ---- kB issue (frags 8..15) ----
    f16x8 kB[8];
#pragma unroll
    for (int f = 0; f < 8; ++f) kB[f] = *(const f16x8*)(kc_base + 4096 + f * 512);
    // ---- QK half A ----
    f32x16 S = {};
#pragma unroll
    for (int kc = 0; kc < 8; ++kc) {
      const f16x8 qf = *(const f16x8*)(qb + kc * 1024);
      S = MFMA32(kA[kc], qf, S);
    }
    // ---- va (V ks0) issue ----
    f16x8 va[8];
#pragma unroll
    for (int dt = 0; dt < 8; ++dt) va[dt] = *(const f16x8*)(vc_base + dt * 1024);
    // ---- QK half B ----
#pragma unroll
    for (int kc = 0; kc < 8; ++kc) {
      const f16x8 qf = *(const f16x8*)(qb + (8 + kc) * 1024);
      S = MFMA32(kB[kc], qf, S);
    }
    // ---- vb (V ks1) issue ----
    f16x8 vb[8];
#pragma unroll
    for (int dt = 0; dt < 8; ++dt)
      vb[dt] = *(const f16x8*)(vc_base + 512 + dt * 1024);

    // ---- in-register softmax + top-2 ----
    const int nbh = nb + hi * 4;
    const float y0 = fmaxf(fmaxf(S[0], S[1]), fmaxf(S[2], S[3]));
    const float y1 = fmaxf(fmaxf(S[4], S[5]), fmaxf(S[6], S[7]));
    const float y2 = fmaxf(fmaxf(S[8], S[9]), fmaxf(S[10], S[11]));
    const float y3 = fmaxf(fmaxf(S[12], S[13]), fmaxf(S[14], S[15]));
    const float t1h = fmaxf(fmaxf(y0, y1), fmaxf(y2, y3));
    int lih = 27;
#pragma unroll
    for (int r = 14; r >= 0; --r) {
      const int rl = (r & 3) + 8 * (r >> 2);
      lih = (S[r] == t1h) ? rl : lih;
    }
    float t2h = -3.0e38f;
#pragma unroll
    for (int r = 0; r < 16; ++r) {
      const int rl = (r & 3) + 8 * (r >> 2);
      t2h = fmaxf(t2h, (lih == rl) ? -3.0e38f : S[r]);
    }
    const int ti_h = nbh + lih;
    float t1 = t1h, t2;
    int ti = ti_h;
    {
      const float o1 = __shfl_xor(t1h, 32);
      const float o2 = __shfl_xor(t2h, 32);
      const int oi = __shfl_xor(ti_h, 32);
      if (o1 > t1h || (o1 == t1h && oi < ti_h)) {
        t1 = o1; ti = oi; t2 = fmaxf(t1h, o2);
      } else {
        t2 = fmaxf(t2h, o1);
      }
    }
    if (t1 > mt1) { mt2 = fmaxf(mt1, t2); mt1 = t1; i1 = ti; }
    else { mt2 = fmaxf(mt2, t1); }
    if (__any(t1 - m_run > 8.f)) {  // defer-max: ~never taken on this data
      const float mnew = fmaxf(m_run, t1);
      const float a = exp2f(m_run - mnew);
      l_run *= a;
      m_run = mnew;
      float av[16];
#pragma unroll
      for (int r = 0; r < 16; ++r)
        av[r] = __shfl(a, (r & 3) + 8 * (r >> 2) + hi * 4);
#pragma unroll
      for (int dt = 0; dt < 8; ++dt)
#pragma unroll
        for (int r = 0; r < 16; ++r) acc[dt][r] *= av[r];
    }
    float P[16];
#pragma unroll
    for (int r = 0; r < 16; ++r) P[r] = exp2f(S[r] - m_run);
    l_run += ((((P[0] + P[1]) + (P[2] + P[3])) + ((P[4] + P[5]) + (P[6] + P[7]))) +
              (((P[8] + P[9]) + (P[10] + P[11])) + ((P[12] + P[13]) + (P[14] + P[15]))));
    // ---- P -> f16 PA fragments ----
    unsigned cc[8], xx[8];
#pragma unroll
    for (int i2 = 0; i2 < 8; ++i2) {
      auto pk = __builtin_amdgcn_cvt_pkrtz(P[2 * i2], P[2 * i2 + 1]);
      cc[i2] = __builtin_bit_cast(unsigned, pk);
    }
#pragma unroll
    for (int i2 = 0; i2 < 8; ++i2)
      xx[i2] = (unsigned)__shfl_xor((int)cc[i2], 32);
    uint32x4 u0, u1;
    u0[0] = hi ? xx[2] : cc[0];
    u0[1] = hi ? xx[3] : cc[1];
    u0[2] = hi ? cc[2] : xx[0];
    u0[3] = hi ? cc[3] : xx[1];
    u1[0] = hi ? xx[6] : cc[4];
    u1[1] = hi ? xx[7] : cc[5];
    u1[2] = hi ? cc[6] : xx[4];
    u1[3] = hi ? cc[7] : xx[5];
    const f16x8 pa0 = __builtin_bit_cast(f16x8, u0);
    const f16x8 pa1 = __builtin_bit_cast(f16x8, u1);

    // ---- PV part 1: pa0 x va ----
#pragma unroll
    for (int dt = 0; dt < 8; ++dt) acc[dt] = MFMA32(pa0, va[dt], acc[dt]);
    // ---- kA(c+1) prefetch ----
    {
      const f16* p = kfbase + (size_t)((c + 1) & 63) * 8192;
#pragma unroll
      for (int f = 0; f < 8; ++f) kA[f] = *(const f16x8*)(p + f * 512);
    }
    // ---- PV part 2: pa1 x vb ----
#pragma unroll
    for (int dt = 0; dt < 8; ++dt) acc[dt] = MFMA32(pa1, vb[dt], acc[dt]);
  }

  // ---- epilogue: dump normalized partials (no in-block merge) ----
  const float lf = l_run + __shfl_xor(l_run, 32);
  const float inv = 1.0f / lf;
  const int myrow = R0 + w * 32 + q;
  if (hi == 0) {
    statA[(size_t)s * M_TOT + myrow] = make_float4(m_run, lf, mt1, mt2);
    statB[(size_t)s * M_TOT + myrow] = i1;
  }
  float ivr[16];
#pragma unroll
  for (int r = 0; r < 16; ++r)
    ivr[r] = __shfl(inv, (r & 3) + 8 * (r >> 2) + hi * 4);
  f16* const pout = pacc + (size_t)s * ((size_t)M_TOT * 256);
#pragma unroll
  for (int dt = 0; dt < 8; ++dt)
#pragma unroll
    for (int r = 0; r < 16; ++r) {
      const int row = R0 + w * 32 + (r & 3) + 8 * (r >> 2) + hi * 4;
      pout[(size_t)row * 256 + dt * 32 + q] = (f16)(acc[dt][r] * ivr[r]);
    }
}

// ---------------- merge: fold 4 n-quarter partials per row ----------------
__global__ __launch_bounds__(256) void merge_kernel(
    const float4* __restrict__ statA, const int* __restrict__ statB,
    const f16* __restrict__ pacc, float* __restrict__ out_q,
    float* __restrict__ out_idx, unsigned* __restrict__ count,
    int* __restrict__ list) {
  const int tid = threadIdx.x;
  const int row = blockIdx.x * 64 + (tid >> 2);
  const int dq = (tid & 3) * 64;
  float4 st[4];
  int idx[4];
  float mstar = -3.0e38f;
#pragma unroll
  for (int s = 0; s < 4; ++s) {
    st[s] = statA[(size_t)s * M_TOT + row];
    idx[s] = statB[(size_t)s * M_TOT + row];
    mstar = fmaxf(mstar, st[s].x);
  }
  float wn[4], den = 0.f;
#pragma unroll
  for (int s = 0; s < 4; ++s) {
    wn[s] = st[s].y * exp2f(st[s].x - mstar);
    den += wn[s];
  }
  const float invden = 1.0f / den;
#pragma unroll
  for (int s = 0; s < 4; ++s) wn[s] *= invden;
  for (int q4 = 0; q4 < 16; ++q4) {
    const size_t off = (size_t)row * 256 + dq + q4 * 4;
    float ox = 0.f, oy = 0.f, oz = 0.f, ow = 0.f;
#pragma unroll
    for (int s = 0; s < 4; ++s) {
      const f16x4 v = *(const f16x4*)(pacc + (size_t)s * ((size_t)M_TOT * 256) + off);
      ox += wn[s] * (float)v[0];
      oy += wn[s] * (float)v[1];
      oz += wn[s] * (float)v[2];
      ow += wn[s] * (float)v[3];
    }
    float4 o;
    o.x = ox; o.y = oy; o.z = oz; o.w = ow;
    *(float4*)(out_q + off) = o;
  }
  if ((tid & 3) == 0) {
    float wm = st[0].z, wm2 = st[0].w;
    int wi = idx[0];
#pragma unroll
    for (int s = 1; s < 4; ++s) {
      if (st[s].z > wm) { wm2 = fmaxf(wm, st[s].w); wm = st[s].z; wi = idx[s]; }
      else wm2 = fmaxf(wm2, st[s].z);
    }
    out_idx[row] = (float)wi;
    if (wm - wm2 <= DELTA) {
      const unsigned pos = atomicAdd(count, 1u);
      list[pos] = row;
    }
  }
}

// ---------------- refine_part: exact fp32 argmax partials, 8 n-slices ----------------
__global__ __launch_bounds__(256) void refine_part_kernel(
    const float* __restrict__ input, const float* __restrict__ ln_w,
    const float* __restrict__ ln_b, const float* __restrict__ embd_t,
    const unsigned* __restrict__ count, const int* __restrict__ list,
    float2* __restrict__ part) {
  __shared__ float xr[4][256];
  __shared__ float redv[4][4];
  __shared__ int redn[4][4];
  const int tid = threadIdx.x;
  const unsigned cnt = *count;
  if (cnt == 0) return;
  const unsigned ntask = ((cnt + 3u) >> 2) * 8u;
  for (unsigned task = blockIdx.x; task < ntask; task += gridDim.x) {
    const unsigned grp = task >> 3;
    const int slice = (int)(task & 7u);
    __syncthreads();
    {
      const int rr = tid >> 6;
      const int sl = tid & 63;
      unsigned ridx = grp * 4u + (unsigned)rr;
      if (ridx >= cnt) ridx = cnt - 1u;
      const int row = list[ridx];
      const float4 a = *(const float4*)(input + (size_t)row * 256 + sl * 4);
      float sm = a.x + a.y + a.z + a.w;
      float ssq = a.x * a.x + a.y * a.y + a.z * a.z + a.w * a.w;
#pragma unroll
      for (int mk = 1; mk <= 32; mk <<= 1) {
        sm += __shfl_xor(sm, mk);
        ssq += __shfl_xor(ssq, mk);
      }
      const float mean = sm * (1.f / 256.f);
      const float var = ssq * (1.f / 256.f) - mean * mean;
      const float rstd = 1.0f / sqrtf(var + LN_EPS);
      const float4 w4 = *(const float4*)(ln_w + sl * 4);
      const float4 b4 = *(const float4*)(ln_b + sl * 4);
      float4 o;
      o.x = (a.x - mean) * rstd * w4.x + b4.x;
      o.y = (a.y - mean) * rstd * w4.y + b4.y;
      o.z = (a.z - mean) * rstd * w4.z + b4.z;
      o.w = (a.w - mean) * rstd * w4.w + b4.w;
      *(float4*)&xr[rr][sl * 4] = o;
    }
    __syncthreads();
    const int n0 = slice * 1024 + tid;
    float dv[4][4] = {};
#pragma unroll 4
    for (int dq = 0; dq < 64; ++dq) {
      const float4 x0 = *(const float4*)&xr[0][dq * 4];
      const float4 x1 = *(const float4*)&xr[1][dq * 4];
      const float4 x2 = *(const float4*)&xr[2][dq * 4];
      const float4 x3 = *(const float4*)&xr[3][dq * 4];
      const float* e0 = embd_t + (size_t)(dq * 4 + 0) * 8192 + n0;
      const float* e1 = embd_t + (size_t)(dq * 4 + 1) * 8192 + n0;
      const float* e2 = embd_t + (size_t)(dq * 4 + 2) * 8192 + n0;
      const float* e3 = embd_t + (size_t)(dq * 4 + 3) * 8192 + n0;
#pragma unroll
      for (int k = 0; k < 4; ++k) {
        const float ea = e0[k * 256];
        const float eb = e1[k * 256];
        const float ec = e2[k * 256];
        const float ed = e3[k * 256];
        dv[k][0] += x0.x * ea + x0.y * eb + x0.z * ec + x0.w * ed;
        dv[k][1] += x1.x * ea + x1.y * eb + x1.z * ec + x1.w * ed;
        dv[k][2] += x2.x * ea + x2.y * eb + x2.z * ec + x2.w * ed;
        dv[k][3] += x3.x * ea + x3.y * eb + x3.z * ec + x3.w * ed;
      }
    }
#pragma unroll
    for (int rr = 0; rr < 4; ++rr) {
      float v = dv[0][rr];
      int nn = n0;
#pragma unroll
      for (int k = 1; k < 4; ++k)
        if (dv[k][rr] > v) { v = dv[k][rr]; nn = n0 + k * 256; }
#pragma unroll
      for (int mk = 1; mk <= 32; mk <<= 1) {
        const float ov = __shfl_xor(v, mk);
        const int on = __shfl_xor(nn, mk);
        if (ov > v || (ov == v && on < nn)) { v = ov; nn = on; }
      }
      if ((tid & 63) == 0) {
        redv[tid >> 6][rr] = v;
        redn[tid >> 6][rr] = nn;
      }
    }
    __syncthreads();
    if (tid < 4) {
      const unsigned ridx = grp * 4u + (unsigned)tid;
      if (ridx < cnt) {
        float v = redv[0][tid];
        int nn = redn[0][tid];
#pragma unroll
        for (int wv = 1; wv < 4; ++wv) {
          const float ov = redv[wv][tid];
          const int on = redn[wv][tid];
          if (ov > v || (ov == v && on < nn)) { v = ov; nn = on; }
        }
        part[ridx * 8u + (unsigned)slice] = make_float2(v, (float)nn);
      }
    }
  }
}

// ---------------- refine_merge: fold 8 slice partials per flagged row ----------------
__global__ __launch_bounds__(256) void refine_merge_kernel(
    float* __restrict__ out_idx, const unsigned* __restrict__ count,
    const int* __restrict__ list, const float2* __restrict__ part) {
  const unsigned cnt = *count;
  for (unsigned i = blockIdx.x * 256u + threadIdx.x; i < cnt;
       i += gridDim.x * 256u) {
    float v = -3.0e38f;
    int nn = 0;
#pragma unroll
    for (int s = 0; s < 8; ++s) {
      const float2 p = part[i * 8u + (unsigned)s];
      const int on = (int)p.y;
      if (p.x > v || (p.x == v && on < nn)) { v = p.x; nn = on; }
    }
    out_idx[list[i]] = (float)nn;
  }
}

extern "C" void kernel_launch(void* const* d_in, const int* in_sizes, int n_in,
                              void* d_out, int out_size, void* d_ws,
                              size_t ws_size, hipStream_t stream) {
  (void)in_sizes;
  (void)n_in;
  (void)out_size;
  (void)ws_size;
  const float* input = (const float*)d_in[0];
  const float* ln_w = (const float*)d_in[1];
  const float* ln_b = (const float*)d_in[2];
  const float* embd = (const float*)d_in[3];
  float* out_q = (float*)d_out;
  float* out_idx = out_q + (size_t)M_TOT * 256;
  char* ws = (char*)d_ws;
  f16* kfrag = (f16*)(ws + WS_KFRAG);
  f16* vfrag = (f16*)(ws + WS_VFRAG);
  unsigned* count = (unsigned*)(ws + WS_COUNT);
  int* list = (int*)(ws + WS_LIST);
  float4* statA = (float4*)(ws + WS_STATA);
  int* statB = (int*)(ws + WS_STATB);
  float* embd_t = (float*)(ws + WS_EMBDT);
  f16* pacc = (f16*)(ws + WS_PACC);
  float2* part = (float2*)(ws + WS_RPART);

  prep_kernel<<<512, 256, 0, stream>>>(embd, kfrag, vfrag, embd_t, count);
  fused_kernel<<<512, 256, 0, stream>>>(input, ln_w, ln_b, kfrag, vfrag,
                                        pacc, statA, statB);
  merge_kernel<<<256, 256, 0, stream>>>(statA, statB, pacc, out_q, out_idx,
                                        count, list);
  refine_part_kernel<<<256, 256, 0, stream>>>(input, ln_w, ln_b, embd_t,
                                              count, list, part);
  refine_merge_kernel<<<16, 256, 0, stream>>>(out_idx, count, list, part);
}

// Round 12
// 367.913 us; speedup vs baseline: 1.4604x; 1.4604x over previous
//
#include <hip/hip_runtime.h>
#include <stdint.h>

#define N_EMB 8192
#define M_TOT 16384
#define DELTA 6e-3f   // top-2 gap threshold in log2-units
#define LN_EPS 1e-5f
#define SCL 0.09016994f  // 0.0625 * log2(e): logits in log2 units

typedef _Float16 f16;
typedef f16 f16x8 __attribute__((ext_vector_type(8)));
typedef f16 f16x4 __attribute__((ext_vector_type(4)));
typedef float f32x16 __attribute__((ext_vector_type(16)));
typedef unsigned uint32x4 __attribute__((ext_vector_type(4)));

// ws layout:
// [0,4MB)  kfrag  [256 chunks][16 frags][64 lanes][8 f16]  (QK A-operand order)
// [4MB,8MB) vfrag [256 chunks][16 frags][64 lanes][8 f16]  (PV B-operand order)
// [8MB,+4) count ; [8MB+64,+64KB) list
// [9MB,10MB) part [rows][8 slices] float2
// [10MB,42MB) embd_t [256 d][8192 n] fp32 (refine transpose)
#define WS_KFRAG 0ul
#define WS_VFRAG (4ul << 20)
#define WS_COUNT (8ul << 20)
#define WS_LIST ((8ul << 20) + 64ul)
#define WS_PART (9ul << 20)
#define WS_EMBDT (10ul << 20)

#define MFMA32(a, b, c) __builtin_amdgcn_mfma_f32_32x32x16_f16(a, b, c, 0, 0, 0)
#define SBAR() __builtin_amdgcn_sched_barrier(0)

typedef const __attribute__((address_space(1))) unsigned int* gsrc_t;
typedef __attribute__((address_space(3))) unsigned int* ldst_t;

// ---------------- prep: fragment layouts (bid<256) + fp32 transpose (bid>=256) ----
__global__ __launch_bounds__(256) void prep_kernel(const float* __restrict__ embd,
                                                   f16* __restrict__ kfrag,
                                                   f16* __restrict__ vfrag,
                                                   float* __restrict__ embd_t,
                                                   unsigned* __restrict__ count) {
  const int t = threadIdx.x;
  const int bid = blockIdx.x;
  if (bid < 256) {
    if (bid == 0 && t == 0) *count = 0u;
    __shared__ f16 tile[32][272];
    const int c = bid;
    {
      const int r = t >> 3;
      const int d0 = (t & 7) * 32;
      const float4* src = (const float4*)(embd + (size_t)(c * 32 + r) * 256 + d0);
#pragma unroll
      for (int qd = 0; qd < 8; ++qd) {
        float4 v = src[qd];
        tile[r][d0 + qd * 4 + 0] = (f16)v.x;
        tile[r][d0 + qd * 4 + 1] = (f16)v.y;
        tile[r][d0 + qd * 4 + 2] = (f16)v.z;
        tile[r][d0 + qd * 4 + 3] = (f16)v.w;
      }
    }
    __syncthreads();
#pragma unroll
    for (int i = 0; i < 4; ++i) {
      const int u = t + i * 256;
      const int kc = u >> 6;
      const int l = u & 63;
      const f16x8 pack = *(const f16x8*)&tile[l & 31][kc * 16 + ((l >> 5) & 1) * 8];
      *(f16x8*)(kfrag + (size_t)c * 8192 + (size_t)u * 8) = pack;
    }
#pragma unroll
    for (int i = 0; i < 4; ++i) {
      const int u = t + i * 256;
      const int fi = u >> 6;
      const int l = u & 63;
      const int dt = fi >> 1, ks = fi & 1;
      f16x8 pack;
#pragma unroll
      for (int j = 0; j < 8; ++j)
        pack[j] = tile[ks * 16 + ((l >> 5) & 1) * 8 + j][dt * 32 + (l & 31)];
      *(f16x8*)(vfrag + (size_t)c * 8192 + (size_t)u * 8) = pack;
    }
  } else {
    __shared__ float ftile[32][257];
    const int c = bid - 256;
    {
      const int r = t >> 3;
      const int d0 = (t & 7) * 32;
      const float4* src = (const float4*)(embd + (size_t)(c * 32 + r) * 256 + d0);
#pragma unroll
      for (int q8 = 0; q8 < 8; ++q8) {
        const float4 v = src[q8];
        ftile[r][d0 + q8 * 4 + 0] = v.x;
        ftile[r][d0 + q8 * 4 + 1] = v.y;
        ftile[r][d0 + q8 * 4 + 2] = v.z;
        ftile[r][d0 + q8 * 4 + 3] = v.w;
      }
    }
    __syncthreads();
    const int r = t & 31;
    const int dh = t >> 5;
#pragma unroll
    for (int dd = 0; dd < 32; ++dd) {
      const int d = dd * 8 + dh;
      embd_t[(size_t)d * 8192 + c * 32 + r] = ftile[r][d];
    }
  }
}

// ---------------- fused: LN + flash softmax-quantize ----------------
// 512 blocks x 256 thr (4 waves = 4 nq quarters), 32 rows/block, 2 blocks/CU.
// R9-proven body. NEW: convoy-breaking stagger — odd-parity blocks sleep ~4K
// cycles once after LN, anti-phasing the two co-resident blocks so one
// block's VMEM/drain phase overlaps the other's VALU/MFMA phases.
// LDS: [0,16384) Q ; [16384+w*8192, +8KB) per-wave V ks0 ; epilogue reuses.
__global__ __launch_bounds__(256, 2) void fused_kernel(
    const float* __restrict__ input, const float* __restrict__ ln_w,
    const float* __restrict__ ln_b, const f16* __restrict__ kfrag,
    const f16* __restrict__ vfrag, float* __restrict__ out_q,
    float* __restrict__ out_idx, unsigned* __restrict__ count,
    int* __restrict__ list) {
  __shared__ __align__(16) char lds[49152];
  const int tid = threadIdx.x;
  const int lane = tid & 63;
  const int w = tid >> 6;  // nq quarter
  const int q = lane & 31;
  const int hi = lane >> 5;
  const int R0 = blockIdx.x * 32;

  const f16* const kfbase = kfrag + (size_t)(w * 64) * 8192 + (size_t)lane * 8;
  const f16* const vfbase = vfrag + (size_t)(w * 64) * 8192 + (size_t)lane * 8;
  char* const stg = lds + 16384 + w * 8192;
  const char* const qb = lds + hi * 512 + q * 16;

  // ---- kA(chunk 0) prefetch: issued before LN, consumed after ----
  f16x8 kA[8];
#pragma unroll
  for (int f = 0; f < 8; ++f) kA[f] = *(const f16x8*)(kfbase + f * 512);

  // ---- LN: 32 rows, 8 thr/row; write Q frags into LDS [0,16K) ----
  {
    const int r = tid >> 3;
    const int seg = tid & 7;
    const float* rowp = input + (size_t)(R0 + r) * 256 + seg * 32;
    float4 xv[8];
    float sm = 0.f, ssq = 0.f;
#pragma unroll
    for (int qd = 0; qd < 8; ++qd) {
      xv[qd] = ((const float4*)rowp)[qd];
      sm += xv[qd].x + xv[qd].y + xv[qd].z + xv[qd].w;
      ssq += xv[qd].x * xv[qd].x + xv[qd].y * xv[qd].y + xv[qd].z * xv[qd].z +
             xv[qd].w * xv[qd].w;
    }
    sm += __shfl_xor(sm, 1);
    sm += __shfl_xor(sm, 2);
    sm += __shfl_xor(sm, 4);
    ssq += __shfl_xor(ssq, 1);
    ssq += __shfl_xor(ssq, 2);
    ssq += __shfl_xor(ssq, 4);
    const float mean = sm * (1.f / 256.f);
    const float var = ssq * (1.f / 256.f) - mean * mean;
    const float rstd = 1.0f / sqrtf(var + LN_EPS);
#pragma unroll
    for (int qd = 0; qd < 8; ++qd) {
      const int d0 = seg * 32 + qd * 4;
      float4 w4 = *(const float4*)(ln_w + d0);
      float4 b4 = *(const float4*)(ln_b + d0);
      f16x4 hv;
      hv[0] = (f16)((((xv[qd].x - mean) * rstd) * w4.x + b4.x) * SCL);
      hv[1] = (f16)((((xv[qd].y - mean) * rstd) * w4.y + b4.y) * SCL);
      hv[2] = (f16)((((xv[qd].z - mean) * rstd) * w4.z + b4.z) * SCL);
      hv[3] = (f16)((((xv[qd].w - mean) * rstd) * w4.w + b4.w) * SCL);
      const int off = (d0 >> 4) * 1024 + ((d0 >> 3) & 1) * 512 + r * 16 + (d0 & 7) * 2;
      *(f16x4*)(lds + off) = hv;
    }
  }
  __syncthreads();

  // ---- convoy breaker: anti-phase the two co-resident blocks ----
  if (blockIdx.x & 1) {
    __builtin_amdgcn_s_sleep(64);  // ~4096 cyc ~= half a chunk period
  }

  f32x16 acc[8] = {};
  float m_run = 0.f, l_run = 0.f, mt1 = -3.0e38f, mt2 = -3.0e38f;
  int i1 = 0;

  for (int c = 0; c < 64; ++c) {
    const int nb = w * 2048 + c * 32;
    // B_pre: raw barrier (no vmcnt drain — kA prefetch stays in flight)
    SBAR();
    __builtin_amdgcn_s_barrier();
    SBAR();
    // ---- stage V ks0-half (frags 2dt) into wave-private LDS, async ----
    {
      const f16* vs = vfbase + (size_t)c * 8192;
#pragma unroll
      for (int dt = 0; dt < 8; ++dt)
        __builtin_amdgcn_global_load_lds((gsrc_t)(vs + dt * 1024),
                                         (ldst_t)(stg + dt * 1024), 16, 0, 0);
    }
    // ---- kB issue (frags 8..15) ----
    f16x8 kB[8];
    {
      const f16* p = kfbase + (size_t)c * 8192 + 4096;
#pragma unroll
      for (int f = 0; f < 8; ++f) kB[f] = *(const f16x8*)(p + f * 512);
    }
    // ---- QK half A ----
    f32x16 S = {};
#pragma unroll
    for (int kc = 0; kc < 8; ++kc) {
      const f16x8 qf = *(const f16x8*)(qb + kc * 1024);
      S = MFMA32(kA[kc], qf, S);
    }
    // ---- V ks1-half register issue (covered by QK-B + softmax) ----
    f16x8 v1[8];
    {
      const f16* p = vfbase + (size_t)c * 8192 + 512;
#pragma unroll
      for (int dt = 0; dt < 8; ++dt) v1[dt] = *(const f16x8*)(p + dt * 1024);
    }
    // ---- QK half B ----
#pragma unroll
    for (int kc = 0; kc < 8; ++kc) {
      const f16x8 qf = *(const f16x8*)(qb + (8 + kc) * 1024);
      S = MFMA32(kB[kc], qf, S);
    }

    // ---- in-register softmax + top-2 ----
    const int nbh = nb + hi * 4;
    const float y0 = fmaxf(fmaxf(S[0], S[1]), fmaxf(S[2], S[3]));
    const float y1 = fmaxf(fmaxf(S[4], S[5]), fmaxf(S[6], S[7]));
    const float y2 = fmaxf(fmaxf(S[8], S[9]), fmaxf(S[10], S[11]));
    const float y3 = fmaxf(fmaxf(S[12], S[13]), fmaxf(S[14], S[15]));
    const float t1h = fmaxf(fmaxf(y0, y1), fmaxf(y2, y3));
    int lih = 27;
#pragma unroll
    for (int r = 14; r >= 0; --r) {
      const int rl = (r & 3) + 8 * (r >> 2);
      lih = (S[r] == t1h) ? rl : lih;
    }
    float t2h = -3.0e38f;
#pragma unroll
    for (int r = 0; r < 16; ++r) {
      const int rl = (r & 3) + 8 * (r >> 2);
      t2h = fmaxf(t2h, (lih == rl) ? -3.0e38f : S[r]);
    }
    const int ti_h = nbh + lih;
    float t1 = t1h, t2;
    int ti = ti_h;
    {
      const float o1 = __shfl_xor(t1h, 32);
      const float o2 = __shfl_xor(t2h, 32);
      const int oi = __shfl_xor(ti_h, 32);
      if (o1 > t1h || (o1 == t1h && oi < ti_h)) {
        t1 = o1; ti = oi; t2 = fmaxf(t1h, o2);
      } else {
        t2 = fmaxf(t2h, o1);
      }
    }
    if (t1 > mt1) { mt2 = fmaxf(mt1, t2); mt1 = t1; i1 = ti; }
    else { mt2 = fmaxf(mt2, t1); }
    if (__any(t1 - m_run > 8.f)) {  // defer-max: ~never taken on this data
      const float mnew = fmaxf(m_run, t1);
      const float a = exp2f(m_run - mnew);
      l_run *= a;
      m_run = mnew;
      float av[16];
#pragma unroll
      for (int r = 0; r < 16; ++r)
        av[r] = __shfl(a, (r & 3) + 8 * (r >> 2) + hi * 4);
#pragma unroll
      for (int dt = 0; dt < 8; ++dt)
#pragma unroll
        for (int r = 0; r < 16; ++r) acc[dt][r] *= av[r];
    }
    float P[16];
#pragma unroll
    for (int r = 0; r < 16; ++r) P[r] = exp2f(S[r] - m_run);
    l_run += ((((P[0] + P[1]) + (P[2] + P[3])) + ((P[4] + P[5]) + (P[6] + P[7]))) +
              (((P[8] + P[9]) + (P[10] + P[11])) + ((P[12] + P[13]) + (P[14] + P[15]))));
    // ---- P -> f16 PA fragments ----
    unsigned cc[8], xx[8];
#pragma unroll
    for (int i2 = 0; i2 < 8; ++i2) {
      auto pk = __builtin_amdgcn_cvt_pkrtz(P[2 * i2], P[2 * i2 + 1]);
      cc[i2] = __builtin_bit_cast(unsigned, pk);
    }
#pragma unroll
    for (int i2 = 0; i2 < 8; ++i2)
      xx[i2] = (unsigned)__shfl_xor((int)cc[i2], 32);
    uint32x4 u0, u1;
    u0[0] = hi ? xx[2] : cc[0];
    u0[1] = hi ? xx[3] : cc[1];
    u0[2] = hi ? cc[2] : xx[0];
    u0[3] = hi ? cc[3] : xx[1];
    u1[0] = hi ? xx[6] : cc[4];
    u1[1] = hi ? xx[7] : cc[5];
    u1[2] = hi ? cc[6] : xx[4];
    u1[3] = hi ? cc[7] : xx[5];
    const f16x8 pa0 = __builtin_bit_cast(f16x8, u0);
    const f16x8 pa1 = __builtin_bit_cast(f16x8, u1);

    // B_mid: staging landed + visible (R7-proven: vmcnt drain + raw barrier)
    asm volatile("s_waitcnt vmcnt(0)" ::: "memory");
    __builtin_amdgcn_s_barrier();
    SBAR();

    // ---- PV: ks0 from private LDS, ks1 from regs ----
#pragma unroll
    for (int dt = 0; dt < 4; ++dt) {
      const f16x8 vb0 = *(const f16x8*)(stg + dt * 1024 + lane * 16);
      acc[dt] = MFMA32(pa0, vb0, acc[dt]);
      acc[dt] = MFMA32(pa1, v1[dt], acc[dt]);
    }
    // ---- kA(c+1) prefetch (in flight across next B_pre) ----
    {
      const f16* p = kfbase + (size_t)((c + 1) & 63) * 8192;
#pragma unroll
      for (int f = 0; f < 8; ++f) kA[f] = *(const f16x8*)(p + f * 512);
    }
#pragma unroll
    for (int dt = 4; dt < 8; ++dt) {
      const f16x8 vb0 = *(const f16x8*)(stg + dt * 1024 + lane * 16);
      acc[dt] = MFMA32(pa0, vb0, acc[dt]);
      acc[dt] = MFMA32(pa1, v1[dt], acc[dt]);
    }
  }

  // ---- epilogue: merge 4 n-quarters (one q-group) ----
  __syncthreads();
  const float lf = l_run + __shfl_xor(l_run, 32);
  float4* statA = (float4*)(lds + 32768);  // [nq][q]
  int* statB = (int*)(lds + 32768 + 2048);
  if (hi == 0) {
    statA[w * 32 + q] = make_float4(m_run, lf, mt1, mt2);
    statB[w * 32 + q] = i1;
  }
  __syncthreads();
  const float4 s0 = statA[0 * 32 + q];
  const float4 s1 = statA[1 * 32 + q];
  const float4 s2 = statA[2 * 32 + q];
  const float4 s3 = statA[3 * 32 + q];
  const float mstar = fmaxf(fmaxf(s0.x, s1.x), fmaxf(s2.x, s3.x));
  const float lstar = s0.y * exp2f(s0.x - mstar) + s1.y * exp2f(s1.x - mstar) +
                      s2.y * exp2f(s2.x - mstar) + s3.y * exp2f(s3.x - mstar);
  const float a_self = exp2f(m_run - mstar);
  const float inv = 1.0f / lstar;
  if (w == 0 && hi == 0) {
    float wm = s0.z, wm2 = s0.w;
    int wi = statB[q];
    if (s1.z > wm) { wm2 = fmaxf(wm, s1.w); wm = s1.z; wi = statB[32 + q]; }
    else wm2 = fmaxf(wm2, s1.z);
    if (s2.z > wm) { wm2 = fmaxf(wm, s2.w); wm = s2.z; wi = statB[64 + q]; }
    else wm2 = fmaxf(wm2, s2.z);
    if (s3.z > wm) { wm2 = fmaxf(wm, s3.w); wm = s3.z; wi = statB[96 + q]; }
    else wm2 = fmaxf(wm2, s3.z);
    const int row = R0 + q;
    out_idx[row] = (float)wi;
    if (wm - wm2 <= DELTA) {
      const unsigned pos = atomicAdd(count, 1u);
      list[pos] = row;
    }
  }
  float av[16], ivr[16];
#pragma unroll
  for (int r = 0; r < 16; ++r) {
    const int qr = (r & 3) + 8 * (r >> 2) + hi * 4;
    av[r] = __shfl(a_self, qr);
    ivr[r] = __shfl(inv, qr);
  }
#pragma unroll
  for (int dt = 0; dt < 8; ++dt)
#pragma unroll
    for (int r = 0; r < 16; ++r) acc[dt][r] *= av[r];
  __syncthreads();
  float* region = (float*)lds;  // 32KB, everything else dead
#define MRG_ADDR(dt, r) (((r & 3) + 8 * (r >> 2) + hi * 4) * 256 + dt * 32 + q)
  if (w == 1) {
#pragma unroll
    for (int dt = 0; dt < 8; ++dt)
#pragma unroll
      for (int r = 0; r < 16; ++r) region[MRG_ADDR(dt, r)] = acc[dt][r];
  }
  __syncthreads();
  if (w == 0) {
#pragma unroll
    for (int dt = 0; dt < 8; ++dt)
#pragma unroll
      for (int r = 0; r < 16; ++r) acc[dt][r] += region[MRG_ADDR(dt, r)];
  }
  __syncthreads();
  if (w == 3) {
#pragma unroll
    for (int dt = 0; dt < 8; ++dt)
#pragma unroll
      for (int r = 0; r < 16; ++r) region[MRG_ADDR(dt, r)] = acc[dt][r];
  }
  __syncthreads();
  if (w == 2) {
#pragma unroll
    for (int dt = 0; dt < 8; ++dt)
#pragma unroll
      for (int r = 0; r < 16; ++r) acc[dt][r] += region[MRG_ADDR(dt, r)];
  }
  __syncthreads();
  if (w == 2) {
#pragma unroll
    for (int dt = 0; dt < 8; ++dt)
#pragma unroll
      for (int r = 0; r < 16; ++r) region[MRG_ADDR(dt, r)] = acc[dt][r];
  }
  __syncthreads();
  if (w == 0) {
#pragma unroll
    for (int dt = 0; dt < 8; ++dt)
#pragma unroll
      for (int r = 0; r < 16; ++r) {
        const int qr = (r & 3) + 8 * (r >> 2) + hi * 4;
        const float v = (acc[dt][r] + region[MRG_ADDR(dt, r)]) * ivr[r];
        out_q[(size_t)(R0 + qr) * 256 + dt * 32 + q] = v;
      }
  }
#undef MRG_ADDR
}

// ---------------- refine_part: exact fp32 argmax partials, 8 n-slices ----------------
__global__ __launch_bounds__(256) void refine_part_kernel(
    const float* __restrict__ input, const float* __restrict__ ln_w,
    const float* __restrict__ ln_b, const float* __restrict__ embd_t,
    const unsigned* __restrict__ count, const int* __restrict__ list,
    float2* __restrict__ part) {
  __shared__ float xr[4][256];
  __shared__ float redv[4][4];
  __shared__ int redn[4][4];
  const int tid = threadIdx.x;
  const unsigned cnt = *count;
  if (cnt == 0) return;
  const unsigned ntask = ((cnt + 3u) >> 2) * 8u;
  for (unsigned task = blockIdx.x; task < ntask; task += gridDim.x) {
    const unsigned grp = task >> 3;
    const int slice = (int)(task & 7u);
    __syncthreads();
    {
      const int rr = tid >> 6;
      const int sl = tid & 63;
      unsigned ridx = grp * 4u + (unsigned)rr;
      if (ridx >= cnt) ridx = cnt - 1u;
      const int row = list[ridx];
      const float4 a = *(const float4*)(input + (size_t)row * 256 + sl * 4);
      float sm = a.x + a.y + a.z + a.w;
      float ssq = a.x * a.x + a.y * a.y + a.z * a.z + a.w * a.w;
#pragma unroll
      for (int mk = 1; mk <= 32; mk <<= 1) {
        sm += __shfl_xor(sm, mk);
        ssq += __shfl_xor(ssq, mk);
      }
      const float mean = sm * (1.f / 256.f);
      const float var = ssq * (1.f / 256.f) - mean * mean;
      const float rstd = 1.0f / sqrtf(var + LN_EPS);
      const float4 w4 = *(const float4*)(ln_w + sl * 4);
      const float4 b4 = *(const float4*)(ln_b + sl * 4);
      float4 o;
      o.x = (a.x - mean) * rstd * w4.x + b4.x;
      o.y = (a.y - mean) * rstd * w4.y + b4.y;
      o.z = (a.z - mean) * rstd * w4.z + b4.z;
      o.w = (a.w - mean) * rstd * w4.w + b4.w;
      *(float4*)&xr[rr][sl * 4] = o;
    }
    __syncthreads();
    const int n0 = slice * 1024 + tid;
    float dv[4][4] = {};
#pragma unroll 4
    for (int dq = 0; dq < 64; ++dq) {
      const float4 x0 = *(const float4*)&xr[0][dq * 4];
      const float4 x1 = *(const float4*)&xr[1][dq * 4];
      const float4 x2 = *(const float4*)&xr[2][dq * 4];
      const float4 x3 = *(const float4*)&xr[3][dq * 4];
      const float* e0 = embd_t + (size_t)(dq * 4 + 0) * 8192 + n0;
      const float* e1 = embd_t + (size_t)(dq * 4 + 1) * 8192 + n0;
      const float* e2 = embd_t + (size_t)(dq * 4 + 2) * 8192 + n0;
      const float* e3 = embd_t + (size_t)(dq * 4 + 3) * 8192 + n0;
#pragma unroll
      for (int k = 0; k < 4; ++k) {
        const float ea = e0[k * 256];
        const float eb = e1[k * 256];
        const float ec = e2[k * 256];
        const float ed = e3[k * 256];
        dv[k][0] += x0.x * ea + x0.y * eb + x0.z * ec + x0.w * ed;
        dv[k][1] += x1.x * ea + x1.y * eb + x1.z * ec + x1.w * ed;
        dv[k][2] += x2.x * ea + x2.y * eb + x2.z * ec + x2.w * ed;
        dv[k][3] += x3.x * ea + x3.y * eb + x3.z * ec + x3.w * ed;
      }
    }
#pragma unroll
    for (int rr = 0; rr < 4; ++rr) {
      float v = dv[0][rr];
      int nn = n0;
#pragma unroll
      for (int k = 1; k < 4; ++k)
        if (dv[k][rr] > v) { v = dv[k][rr]; nn = n0 + k * 256; }
#pragma unroll
      for (int mk = 1; mk <= 32; mk <<= 1) {
        const float ov = __shfl_xor(v, mk);
        const int on = __shfl_xor(nn, mk);
        if (ov > v || (ov == v && on < nn)) { v = ov; nn = on; }
      }
      if ((tid & 63) == 0) {
        redv[tid >> 6][rr] = v;
        redn[tid >> 6][rr] = nn;
      }
    }
    __syncthreads();
    if (tid < 4) {
      const unsigned ridx = grp * 4u + (unsigned)tid;
      if (ridx < cnt) {
        float v = redv[0][tid];
        int nn = redn[0][tid];
#pragma unroll
        for (int wv = 1; wv < 4; ++wv) {
          const float ov = redv[wv][tid];
          const int on = redn[wv][tid];
          if (ov > v || (ov == v && on < nn)) { v = ov; nn = on; }
        }
        part[ridx * 8u + (unsigned)slice] = make_float2(v, (float)nn);
      }
    }
  }
}

// ---------------- refine_merge: fold 8 slice partials per flagged row ----------------
__global__ __launch_bounds__(256) void refine_merge_kernel(
    float* __restrict__ out_idx, const unsigned* __restrict__ count,
    const int* __restrict__ list, const float2* __restrict__ part) {
  const unsigned cnt = *count;
  for (unsigned i = blockIdx.x * 256u + threadIdx.x; i < cnt;
       i += gridDim.x * 256u) {
    float v = -3.0e38f;
    int nn = 0;
#pragma unroll
    for (int s = 0; s < 8; ++s) {
      const float2 p = part[i * 8u + (unsigned)s];
      const int on = (int)p.y;
      if (p.x > v || (p.x == v && on < nn)) { v = p.x; nn = on; }
    }
    out_idx[list[i]] = (float)nn;
  }
}

extern "C" void kernel_launch(void* const* d_in, const int* in_sizes, int n_in,
                              void* d_out, int out_size, void* d_ws,
                              size_t ws_size, hipStream_t stream) {
  (void)in_sizes;
  (void)n_in;
  (void)out_size;
  (void)ws_size;
  const float* input = (const float*)d_in[0];
  const float* ln_w = (const float*)d_in[1];
  const float* ln_b = (const float*)d_in[2];
  const float* embd = (const float*)d_in[3];
  float* out_q = (float*)d_out;
  float* out_idx = out_q + (size_t)M_TOT * 256;
  char* ws = (char*)d_ws;
  f16* kfrag = (f16*)(ws + WS_KFRAG);
  f16* vfrag = (f16*)(ws + WS_VFRAG);
  unsigned* count = (unsigned*)(ws + WS_COUNT);
  int* list = (int*)(ws + WS_LIST);
  float2* part = (float2*)(ws + WS_PART);
  float* embd_t = (float*)(ws + WS_EMBDT);

  prep_kernel<<<512, 256, 0, stream>>>(embd, kfrag, vfrag, embd_t, count);
  fused_kernel<<<512, 256, 0, stream>>>(input, ln_w, ln_b, kfrag, vfrag,
                                        out_q, out_idx, count, list);
  refine_part_kernel<<<256, 256, 0, stream>>>(input, ln_w, ln_b, embd_t,
                                              count, list, part);
  refine_merge_kernel<<<16, 256, 0, stream>>>(out_idx, count, list, part);
}

// Round 13
// 347.735 us; speedup vs baseline: 1.5451x; 1.0580x over previous
//
#include <hip/hip_runtime.h>
#include <stdint.h>

#define N_EMB 8192
#define M_TOT 16384
#define DELTA 6e-3f   // top-2 gap threshold in log2-units
#define LN_EPS 1e-5f
#define SCL 0.09016994f  // 0.0625 * log2(e): logits in log2 units

typedef _Float16 f16;
typedef f16 f16x8 __attribute__((ext_vector_type(8)));
typedef f16 f16x4 __attribute__((ext_vector_type(4)));
typedef float f32x16 __attribute__((ext_vector_type(16)));
typedef unsigned uint32x4 __attribute__((ext_vector_type(4)));

// ws layout:
// [0,4MB)  kfrag  [256 chunks][16 frags][64 lanes][8 f16]  (QK A-operand order)
// [4MB,8MB) vfrag [256 chunks][16 frags][64 lanes][8 f16]  (PV B-operand order)
// [8MB,+4) count ; [8MB+64,+64KB) list
// [9MB,10MB) part [rows][8 slices] float2
// [10MB,42MB) embd_t [256 d][8192 n] fp32 (refine transpose)
#define WS_KFRAG 0ul
#define WS_VFRAG (4ul << 20)
#define WS_COUNT (8ul << 20)
#define WS_LIST ((8ul << 20) + 64ul)
#define WS_PART (9ul << 20)
#define WS_EMBDT (10ul << 20)

#define MFMA32(a, b, c) __builtin_amdgcn_mfma_f32_32x32x16_f16(a, b, c, 0, 0, 0)
#define SBAR() __builtin_amdgcn_sched_barrier(0)

// ---------------- prep: fragment layouts (bid<256) + fp32 transpose (bid>=256) ----
__global__ __launch_bounds__(256) void prep_kernel(const float* __restrict__ embd,
                                                   f16* __restrict__ kfrag,
                                                   f16* __restrict__ vfrag,
                                                   float* __restrict__ embd_t,
                                                   unsigned* __restrict__ count) {
  const int t = threadIdx.x;
  const int bid = blockIdx.x;
  if (bid < 256) {
    if (bid == 0 && t == 0) *count = 0u;
    __shared__ f16 tile[32][272];
    const int c = bid;
    {
      const int r = t >> 3;
      const int d0 = (t & 7) * 32;
      const float4* src = (const float4*)(embd + (size_t)(c * 32 + r) * 256 + d0);
#pragma unroll
      for (int qd = 0; qd < 8; ++qd) {
        float4 v = src[qd];
        tile[r][d0 + qd * 4 + 0] = (f16)v.x;
        tile[r][d0 + qd * 4 + 1] = (f16)v.y;
        tile[r][d0 + qd * 4 + 2] = (f16)v.z;
        tile[r][d0 + qd * 4 + 3] = (f16)v.w;
      }
    }
    __syncthreads();
#pragma unroll
    for (int i = 0; i < 4; ++i) {
      const int u = t + i * 256;
      const int kc = u >> 6;
      const int l = u & 63;
      const f16x8 pack = *(const f16x8*)&tile[l & 31][kc * 16 + ((l >> 5) & 1) * 8];
      *(f16x8*)(kfrag + (size_t)c * 8192 + (size_t)u * 8) = pack;
    }
#pragma unroll
    for (int i = 0; i < 4; ++i) {
      const int u = t + i * 256;
      const int fi = u >> 6;
      const int l = u & 63;
      const int dt = fi >> 1, ks = fi & 1;
      f16x8 pack;
#pragma unroll
      for (int j = 0; j < 8; ++j)
        pack[j] = tile[ks * 16 + ((l >> 5) & 1) * 8 + j][dt * 32 + (l & 31)];
      *(f16x8*)(vfrag + (size_t)c * 8192 + (size_t)u * 8) = pack;
    }
  } else {
    __shared__ float ftile[32][257];
    const int c = bid - 256;
    {
      const int r = t >> 3;
      const int d0 = (t & 7) * 32;
      const float4* src = (const float4*)(embd + (size_t)(c * 32 + r) * 256 + d0);
#pragma unroll
      for (int q8 = 0; q8 < 8; ++q8) {
        const float4 v = src[q8];
        ftile[r][d0 + q8 * 4 + 0] = v.x;
        ftile[r][d0 + q8 * 4 + 1] = v.y;
        ftile[r][d0 + q8 * 4 + 2] = v.z;
        ftile[r][d0 + q8 * 4 + 3] = v.w;
      }
    }
    __syncthreads();
    const int r = t & 31;
    const int dh = t >> 5;
#pragma unroll
    for (int dd = 0; dd < 32; ++dd) {
      const int d = dd * 8 + dh;
      embd_t[(size_t)d * 8192 + c * 32 + r] = ftile[r][d];
    }
  }
}

// ---------------- fused: LN + flash softmax-quantize ----------------
// 512 blocks x 256 thr (4 waves = 4 nq quarters), 32 rows/block, 2 blocks/CU.
// ONE raw s_barrier per chunk (locality pacing only; no LDS writes in loop,
// so no data-safety barrier needed). All K/V register-loaded: V in two 32-reg
// batches (va=ks0, vb=ks1), kA prefetched across the chunk boundary. Top-2 /
// argmax bookkeeping moved AFTER the PV MFMAs (executes in MFMA shadow).
// LDS: [0,16384) Q frags (read-only after LN); epilogue reuses [0,36K).
__global__ __launch_bounds__(256, 2) void fused_kernel(
    const float* __restrict__ input, const float* __restrict__ ln_w,
    const float* __restrict__ ln_b, const f16* __restrict__ kfrag,
    const f16* __restrict__ vfrag, float* __restrict__ out_q,
    float* __restrict__ out_idx, unsigned* __restrict__ count,
    int* __restrict__ list) {
  __shared__ __align__(16) char lds[36864];
  const int tid = threadIdx.x;
  const int lane = tid & 63;
  const int w = tid >> 6;  // nq quarter
  const int q = lane & 31;
  const int hi = lane >> 5;
  const int R0 = blockIdx.x * 32;

  const f16* const kfbase = kfrag + (size_t)(w * 64) * 8192 + (size_t)lane * 8;
  const f16* const vfbase = vfrag + (size_t)(w * 64) * 8192 + (size_t)lane * 8;
  const char* const qb = lds + hi * 512 + q * 16;

  // ---- kA(chunk 0) prefetch: issued before LN, consumed after ----
  f16x8 kA[8];
#pragma unroll
  for (int f = 0; f < 8; ++f) kA[f] = *(const f16x8*)(kfbase + f * 512);

  // ---- LN: 32 rows, 8 thr/row; write Q frags into LDS [0,16K) ----
  {
    const int r = tid >> 3;
    const int seg = tid & 7;
    const float* rowp = input + (size_t)(R0 + r) * 256 + seg * 32;
    float4 xv[8];
    float sm = 0.f, ssq = 0.f;
#pragma unroll
    for (int qd = 0; qd < 8; ++qd) {
      xv[qd] = ((const float4*)rowp)[qd];
      sm += xv[qd].x + xv[qd].y + xv[qd].z + xv[qd].w;
      ssq += xv[qd].x * xv[qd].x + xv[qd].y * xv[qd].y + xv[qd].z * xv[qd].z +
             xv[qd].w * xv[qd].w;
    }
    sm += __shfl_xor(sm, 1);
    sm += __shfl_xor(sm, 2);
    sm += __shfl_xor(sm, 4);
    ssq += __shfl_xor(ssq, 1);
    ssq += __shfl_xor(ssq, 2);
    ssq += __shfl_xor(ssq, 4);
    const float mean = sm * (1.f / 256.f);
    const float var = ssq * (1.f / 256.f) - mean * mean;
    const float rstd = 1.0f / sqrtf(var + LN_EPS);
#pragma unroll
    for (int qd = 0; qd < 8; ++qd) {
      const int d0 = seg * 32 + qd * 4;
      float4 w4 = *(const float4*)(ln_w + d0);
      float4 b4 = *(const float4*)(ln_b + d0);
      f16x4 hv;
      hv[0] = (f16)((((xv[qd].x - mean) * rstd) * w4.x + b4.x) * SCL);
      hv[1] = (f16)((((xv[qd].y - mean) * rstd) * w4.y + b4.y) * SCL);
      hv[2] = (f16)((((xv[qd].z - mean) * rstd) * w4.z + b4.z) * SCL);
      hv[3] = (f16)((((xv[qd].w - mean) * rstd) * w4.w + b4.w) * SCL);
      const int off = (d0 >> 4) * 1024 + ((d0 >> 3) & 1) * 512 + r * 16 + (d0 & 7) * 2;
      *(f16x4*)(lds + off) = hv;
    }
  }
  __syncthreads();

  f32x16 acc[8] = {};
  float m_run = 0.f, l_run = 0.f, mt1 = -3.0e38f, mt2 = -3.0e38f;
  int i1 = 0;

  for (int c = 0; c < 64; ++c) {
    const int nb = w * 2048 + c * 32;
    const f16* const kc_base = kfbase + (size_t)c * 8192;
    const f16* const vc_base = vfbase + (size_t)c * 8192;
    // B_pre: raw barrier — locality pacing only (kA prefetch stays in flight)
    SBAR();
    __builtin_amdgcn_s_barrier();
    SBAR();
    // ---- kB issue (frags 8..15) ----
    f16x8 kB[8];
#pragma unroll
    for (int f = 0; f < 8; ++f) kB[f] = *(const f16x8*)(kc_base + 4096 + f * 512);
    // ---- QK half A ----
    f32x16 S = {};
#pragma unroll
    for (int kc = 0; kc < 8; ++kc) {
      const f16x8 qf = *(const f16x8*)(qb + kc * 1024);
      S = MFMA32(kA[kc], qf, S);
    }
    // ---- va (V ks0) issue: consumed in PV-1 ----
    f16x8 va[8];
#pragma unroll
    for (int dt = 0; dt < 8; ++dt) va[dt] = *(const f16x8*)(vc_base + dt * 1024);
    // ---- QK half B ----
#pragma unroll
    for (int kc = 0; kc < 8; ++kc) {
      const f16x8 qf = *(const f16x8*)(qb + (8 + kc) * 1024);
      S = MFMA32(kB[kc], qf, S);
    }
    // ---- vb (V ks1) issue: consumed in PV-2 ----
    f16x8 vb[8];
#pragma unroll
    for (int dt = 0; dt < 8; ++dt)
      vb[dt] = *(const f16x8*)(vc_base + 512 + dt * 1024);

    // ---- fast path: tree max only (index/top-2 deferred to MFMA shadow) ----
    const float y0 = fmaxf(fmaxf(S[0], S[1]), fmaxf(S[2], S[3]));
    const float y1 = fmaxf(fmaxf(S[4], S[5]), fmaxf(S[6], S[7]));
    const float y2 = fmaxf(fmaxf(S[8], S[9]), fmaxf(S[10], S[11]));
    const float y3 = fmaxf(fmaxf(S[12], S[13]), fmaxf(S[14], S[15]));
    const float t1h = fmaxf(fmaxf(y0, y1), fmaxf(y2, y3));
    const float o1 = __shfl_xor(t1h, 32);
    const float t1max = fmaxf(t1h, o1);
    if (__any(t1max - m_run > 8.f)) {  // defer-max: ~never taken on this data
      const float mnew = fmaxf(m_run, t1max);
      const float a = exp2f(m_run - mnew);
      l_run *= a;
      m_run = mnew;
      float av[16];
#pragma unroll
      for (int r = 0; r < 16; ++r)
        av[r] = __shfl(a, (r & 3) + 8 * (r >> 2) + hi * 4);
#pragma unroll
      for (int dt = 0; dt < 8; ++dt)
#pragma unroll
        for (int r = 0; r < 16; ++r) acc[dt][r] *= av[r];
    }
    float P[16];
#pragma unroll
    for (int r = 0; r < 16; ++r) P[r] = exp2f(S[r] - m_run);
    l_run += ((((P[0] + P[1]) + (P[2] + P[3])) + ((P[4] + P[5]) + (P[6] + P[7]))) +
              (((P[8] + P[9]) + (P[10] + P[11])) + ((P[12] + P[13]) + (P[14] + P[15]))));
    // ---- P -> f16 PA fragments ----
    unsigned cc[8], xx[8];
#pragma unroll
    for (int i2 = 0; i2 < 8; ++i2) {
      auto pk = __builtin_amdgcn_cvt_pkrtz(P[2 * i2], P[2 * i2 + 1]);
      cc[i2] = __builtin_bit_cast(unsigned, pk);
    }
#pragma unroll
    for (int i2 = 0; i2 < 8; ++i2)
      xx[i2] = (unsigned)__shfl_xor((int)cc[i2], 32);
    uint32x4 u0, u1;
    u0[0] = hi ? xx[2] : cc[0];
    u0[1] = hi ? xx[3] : cc[1];
    u0[2] = hi ? cc[2] : xx[0];
    u0[3] = hi ? cc[3] : xx[1];
    u1[0] = hi ? xx[6] : cc[4];
    u1[1] = hi ? xx[7] : cc[5];
    u1[2] = hi ? cc[6] : xx[4];
    u1[3] = hi ? cc[7] : xx[5];
    const f16x8 pa0 = __builtin_bit_cast(f16x8, u0);
    const f16x8 pa1 = __builtin_bit_cast(f16x8, u1);

    // ---- PV part 1: pa0 x va ----
#pragma unroll
    for (int dt = 0; dt < 8; ++dt) acc[dt] = MFMA32(pa0, va[dt], acc[dt]);
    // ---- kA(c+1) prefetch ----
    {
      const f16* p = kfbase + (size_t)((c + 1) & 63) * 8192;
#pragma unroll
      for (int f = 0; f < 8; ++f) kA[f] = *(const f16x8*)(p + f * 512);
    }
    // ---- PV part 2: pa1 x vb ----
#pragma unroll
    for (int dt = 0; dt < 8; ++dt) acc[dt] = MFMA32(pa1, vb[dt], acc[dt]);

    // ---- shadow bookkeeping: argmax index + top-2 (hidden under MFMAs) ----
    {
      const int nbh = nb + hi * 4;
      int lih = 27;
#pragma unroll
      for (int r = 14; r >= 0; --r) {
        const int rl = (r & 3) + 8 * (r >> 2);
        lih = (S[r] == t1h) ? rl : lih;
      }
      float t2h = -3.0e38f;
#pragma unroll
      for (int r = 0; r < 16; ++r) {
        const int rl = (r & 3) + 8 * (r >> 2);
        t2h = fmaxf(t2h, (lih == rl) ? -3.0e38f : S[r]);
      }
      const int ti_h = nbh + lih;
      const float o2 = __shfl_xor(t2h, 32);
      const int oi = __shfl_xor(ti_h, 32);
      float t1, t2;
      int ti;
      if (o1 > t1h || (o1 == t1h && oi < ti_h)) {
        t1 = o1; ti = oi; t2 = fmaxf(t1h, o2);
      } else {
        t1 = t1h; ti = ti_h; t2 = fmaxf(t2h, o1);
      }
      if (t1 > mt1) { mt2 = fmaxf(mt1, t2); mt1 = t1; i1 = ti; }
      else { mt2 = fmaxf(mt2, t1); }
    }
  }

  // ---- epilogue: merge 4 n-quarters (one q-group) ----
  __syncthreads();
  const float lf = l_run + __shfl_xor(l_run, 32);
  float4* statA = (float4*)(lds + 32768);  // [nq][q]
  int* statB = (int*)(lds + 32768 + 2048);
  if (hi == 0) {
    statA[w * 32 + q] = make_float4(m_run, lf, mt1, mt2);
    statB[w * 32 + q] = i1;
  }
  __syncthreads();
  const float4 s0 = statA[0 * 32 + q];
  const float4 s1 = statA[1 * 32 + q];
  const float4 s2 = statA[2 * 32 + q];
  const float4 s3 = statA[3 * 32 + q];
  const float mstar = fmaxf(fmaxf(s0.x, s1.x), fmaxf(s2.x, s3.x));
  const float lstar = s0.y * exp2f(s0.x - mstar) + s1.y * exp2f(s1.x - mstar) +
                      s2.y * exp2f(s2.x - mstar) + s3.y * exp2f(s3.x - mstar);
  const float a_self = exp2f(m_run - mstar);
  const float inv = 1.0f / lstar;
  if (w == 0 && hi == 0) {
    float wm = s0.z, wm2 = s0.w;
    int wi = statB[q];
    if (s1.z > wm) { wm2 = fmaxf(wm, s1.w); wm = s1.z; wi = statB[32 + q]; }
    else wm2 = fmaxf(wm2, s1.z);
    if (s2.z > wm) { wm2 = fmaxf(wm, s2.w); wm = s2.z; wi = statB[64 + q]; }
    else wm2 = fmaxf(wm2, s2.z);
    if (s3.z > wm) { wm2 = fmaxf(wm, s3.w); wm = s3.z; wi = statB[96 + q]; }
    else wm2 = fmaxf(wm2, s3.z);
    const int row = R0 + q;
    out_idx[row] = (float)wi;
    if (wm - wm2 <= DELTA) {
      const unsigned pos = atomicAdd(count, 1u);
      list[pos] = row;
    }
  }
  float av[16], ivr[16];
#pragma unroll
  for (int r = 0; r < 16; ++r) {
    const int qr = (r & 3) + 8 * (r >> 2) + hi * 4;
    av[r] = __shfl(a_self, qr);
    ivr[r] = __shfl(inv, qr);
  }
#pragma unroll
  for (int dt = 0; dt < 8; ++dt)
#pragma unroll
    for (int r = 0; r < 16; ++r) acc[dt][r] *= av[r];
  __syncthreads();
  float* region = (float*)lds;  // 32KB, everything else dead
#define MRG_ADDR(dt, r) (((r & 3) + 8 * (r >> 2) + hi * 4) * 256 + dt * 32 + q)
  if (w == 1) {
#pragma unroll
    for (int dt = 0; dt < 8; ++dt)
#pragma unroll
      for (int r = 0; r < 16; ++r) region[MRG_ADDR(dt, r)] = acc[dt][r];
  }
  __syncthreads();
  if (w == 0) {
#pragma unroll
    for (int dt = 0; dt < 8; ++dt)
#pragma unroll
      for (int r = 0; r < 16; ++r) acc[dt][r] += region[MRG_ADDR(dt, r)];
  }
  __syncthreads();
  if (w == 3) {
#pragma unroll
    for (int dt = 0; dt < 8; ++dt)
#pragma unroll
      for (int r = 0; r < 16; ++r) region[MRG_ADDR(dt, r)] = acc[dt][r];
  }
  __syncthreads();
  if (w == 2) {
#pragma unroll
    for (int dt = 0; dt < 8; ++dt)
#pragma unroll
      for (int r = 0; r < 16; ++r) acc[dt][r] += region[MRG_ADDR(dt, r)];
  }
  __syncthreads();
  if (w == 2) {
#pragma unroll
    for (int dt = 0; dt < 8; ++dt)
#pragma unroll
      for (int r = 0; r < 16; ++r) region[MRG_ADDR(dt, r)] = acc[dt][r];
  }
  __syncthreads();
  if (w == 0) {
#pragma unroll
    for (int dt = 0; dt < 8; ++dt)
#pragma unroll
      for (int r = 0; r < 16; ++r) {
        const int qr = (r & 3) + 8 * (r >> 2) + hi * 4;
        const float v = (acc[dt][r] + region[MRG_ADDR(dt, r)]) * ivr[r];
        out_q[(size_t)(R0 + qr) * 256 + dt * 32 + q] = v;
      }
  }
#undef MRG_ADDR
}

// ---------------- refine_part: exact fp32 argmax partials, 8 n-slices ----------------
__global__ __launch_bounds__(256) void refine_part_kernel(
    const float* __restrict__ input, const float* __restrict__ ln_w,
    const float* __restrict__ ln_b, const float* __restrict__ embd_t,
    const unsigned* __restrict__ count, const int* __restrict__ list,
    float2* __restrict__ part) {
  __shared__ float xr[4][256];
  __shared__ float redv[4][4];
  __shared__ int redn[4][4];
  const int tid = threadIdx.x;
  const unsigned cnt = *count;
  if (cnt == 0) return;
  const unsigned ntask = ((cnt + 3u) >> 2) * 8u;
  for (unsigned task = blockIdx.x; task < ntask; task += gridDim.x) {
    const unsigned grp = task >> 3;
    const int slice = (int)(task & 7u);
    __syncthreads();
    {
      const int rr = tid >> 6;
      const int sl = tid & 63;
      unsigned ridx = grp * 4u + (unsigned)rr;
      if (ridx >= cnt) ridx = cnt - 1u;
      const int row = list[ridx];
      const float4 a = *(const float4*)(input + (size_t)row * 256 + sl * 4);
      float sm = a.x + a.y + a.z + a.w;
      float ssq = a.x * a.x + a.y * a.y + a.z * a.z + a.w * a.w;
#pragma unroll
      for (int mk = 1; mk <= 32; mk <<= 1) {
        sm += __shfl_xor(sm, mk);
        ssq += __shfl_xor(ssq, mk);
      }
      const float mean = sm * (1.f / 256.f);
      const float var = ssq * (1.f / 256.f) - mean * mean;
      const float rstd = 1.0f / sqrtf(var + LN_EPS);
      const float4 w4 = *(const float4*)(ln_w + sl * 4);
      const float4 b4 = *(const float4*)(ln_b + sl * 4);
      float4 o;
      o.x = (a.x - mean) * rstd * w4.x + b4.x;
      o.y = (a.y - mean) * rstd * w4.y + b4.y;
      o.z = (a.z - mean) * rstd * w4.z + b4.z;
      o.w = (a.w - mean) * rstd * w4.w + b4.w;
      *(float4*)&xr[rr][sl * 4] = o;
    }
    __syncthreads();
    const int n0 = slice * 1024 + tid;
    float dv[4][4] = {};
#pragma unroll 4
    for (int dq = 0; dq < 64; ++dq) {
      const float4 x0 = *(const float4*)&xr[0][dq * 4];
      const float4 x1 = *(const float4*)&xr[1][dq * 4];
      const float4 x2 = *(const float4*)&xr[2][dq * 4];
      const float4 x3 = *(const float4*)&xr[3][dq * 4];
      const float* e0 = embd_t + (size_t)(dq * 4 + 0) * 8192 + n0;
      const float* e1 = embd_t + (size_t)(dq * 4 + 1) * 8192 + n0;
      const float* e2 = embd_t + (size_t)(dq * 4 + 2) * 8192 + n0;
      const float* e3 = embd_t + (size_t)(dq * 4 + 3) * 8192 + n0;
#pragma unroll
      for (int k = 0; k < 4; ++k) {
        const float ea = e0[k * 256];
        const float eb = e1[k * 256];
        const float ec = e2[k * 256];
        const float ed = e3[k * 256];
        dv[k][0] += x0.x * ea + x0.y * eb + x0.z * ec + x0.w * ed;
        dv[k][1] += x1.x * ea + x1.y * eb + x1.z * ec + x1.w * ed;
        dv[k][2] += x2.x * ea + x2.y * eb + x2.z * ec + x2.w * ed;
        dv[k][3] += x3.x * ea + x3.y * eb + x3.z * ec + x3.w * ed;
      }
    }
#pragma unroll
    for (int rr = 0; rr < 4; ++rr) {
      float v = dv[0][rr];
      int nn = n0;
#pragma unroll
      for (int k = 1; k < 4; ++k)
        if (dv[k][rr] > v) { v = dv[k][rr]; nn = n0 + k * 256; }
#pragma unroll
      for (int mk = 1; mk <= 32; mk <<= 1) {
        const float ov = __shfl_xor(v, mk);
        const int on = __shfl_xor(nn, mk);
        if (ov > v || (ov == v && on < nn)) { v = ov; nn = on; }
      }
      if ((tid & 63) == 0) {
        redv[tid >> 6][rr] = v;
        redn[tid >> 6][rr] = nn;
      }
    }
    __syncthreads();
    if (tid < 4) {
      const unsigned ridx = grp * 4u + (unsigned)tid;
      if (ridx < cnt) {
        float v = redv[0][tid];
        int nn = redn[0][tid];
#pragma unroll
        for (int wv = 1; wv < 4; ++wv) {
          const float ov = redv[wv][tid];
          const int on = redn[wv][tid];
          if (ov > v || (ov == v && on < nn)) { v = ov; nn = on; }
        }
        part[ridx * 8u + (unsigned)slice] = make_float2(v, (float)nn);
      }
    }
  }
}

// ---------------- refine_merge: fold 8 slice partials per flagged row ----------------
__global__ __launch_bounds__(256) void refine_merge_kernel(
    float* __restrict__ out_idx, const unsigned* __restrict__ count,
    const int* __restrict__ list, const float2* __restrict__ part) {
  const unsigned cnt = *count;
  for (unsigned i = blockIdx.x * 256u + threadIdx.x; i < cnt;
       i += gridDim.x * 256u) {
    float v = -3.0e38f;
    int nn = 0;
#pragma unroll
    for (int s = 0; s < 8; ++s) {
      const float2 p = part[i * 8u + (unsigned)s];
      const int on = (int)p.y;
      if (p.x > v || (p.x == v && on < nn)) { v = p.x; nn = on; }
    }
    out_idx[list[i]] = (float)nn;
  }
}

extern "C" void kernel_launch(void* const* d_in, const int* in_sizes, int n_in,
                              void* d_out, int out_size, void* d_ws,
                              size_t ws_size, hipStream_t stream) {
  (void)in_sizes;
  (void)n_in;
  (void)out_size;
  (void)ws_size;
  const float* input = (const float*)d_in[0];
  const float* ln_w = (const float*)d_in[1];
  const float* ln_b = (const float*)d_in[2];
  const float* embd = (const float*)d_in[3];
  float* out_q = (float*)d_out;
  float* out_idx = out_q + (size_t)M_TOT * 256;
  char* ws = (char*)d_ws;
  f16* kfrag = (f16*)(ws + WS_KFRAG);
  f16* vfrag = (f16*)(ws + WS_VFRAG);
  unsigned* count = (unsigned*)(ws + WS_COUNT);
  int* list = (int*)(ws + WS_LIST);
  float2* part = (float2*)(ws + WS_PART);
  float* embd_t = (float*)(ws + WS_EMBDT);

  prep_kernel<<<512, 256, 0, stream>>>(embd, kfrag, vfrag, embd_t, count);
  fused_kernel<<<512, 256, 0, stream>>>(input, ln_w, ln_b, kfrag, vfrag,
                                        out_q, out_idx, count, list);
  refine_part_kernel<<<256, 256, 0, stream>>>(input, ln_w, ln_b, embd_t,
                                              count, list, part);
  refine_merge_kernel<<<16, 256, 0, stream>>>(out_idx, count, list, part);
}

// Round 14
// 279.406 us; speedup vs baseline: 1.9230x; 1.2446x over previous
//
#include <hip/hip_runtime.h>
#include <stdint.h>

#define N_EMB 8192
#define M_TOT 16384
#define DELTA 6e-3f   // top-2 gap threshold in log2-units
#define LN_EPS 1e-5f
#define SCL 0.09016994f  // 0.0625 * log2(e): logits in log2 units

typedef _Float16 f16;
typedef f16 f16x8 __attribute__((ext_vector_type(8)));
typedef f16 f16x4 __attribute__((ext_vector_type(4)));
typedef float f32x16 __attribute__((ext_vector_type(16)));
typedef unsigned uint32x4 __attribute__((ext_vector_type(4)));

// ws layout:
// [0,4MB)  kfrag  [256 chunks][16 frags][64 lanes][8 f16]  (QK A-operand order)
// [4MB,8MB) vfrag [256 chunks][16 frags][64 lanes][8 f16]  (PV B-operand order)
// [8MB,+4) count ; [8MB+64,+64KB) list
// [9MB,10MB) part [rows][8 slices] float2
// [10MB,42MB) embd_t [256 d][8192 n] fp32 (refine transpose)
#define WS_KFRAG 0ul
#define WS_VFRAG (4ul << 20)
#define WS_COUNT (8ul << 20)
#define WS_LIST ((8ul << 20) + 64ul)
#define WS_PART (9ul << 20)
#define WS_EMBDT (10ul << 20)

#define MFMA32(a, b, c) __builtin_amdgcn_mfma_f32_32x32x16_f16(a, b, c, 0, 0, 0)
#define SBAR() __builtin_amdgcn_sched_barrier(0)

// ---------------- prep: fragment layouts (bid<256) + fp32 transpose (bid>=256) ----
__global__ __launch_bounds__(256) void prep_kernel(const float* __restrict__ embd,
                                                   f16* __restrict__ kfrag,
                                                   f16* __restrict__ vfrag,
                                                   float* __restrict__ embd_t,
                                                   unsigned* __restrict__ count) {
  const int t = threadIdx.x;
  const int bid = blockIdx.x;
  if (bid < 256) {
    if (bid == 0 && t == 0) *count = 0u;
    __shared__ f16 tile[32][272];
    const int c = bid;
    {
      const int r = t >> 3;
      const int d0 = (t & 7) * 32;
      const float4* src = (const float4*)(embd + (size_t)(c * 32 + r) * 256 + d0);
#pragma unroll
      for (int qd = 0; qd < 8; ++qd) {
        float4 v = src[qd];
        tile[r][d0 + qd * 4 + 0] = (f16)v.x;
        tile[r][d0 + qd * 4 + 1] = (f16)v.y;
        tile[r][d0 + qd * 4 + 2] = (f16)v.z;
        tile[r][d0 + qd * 4 + 3] = (f16)v.w;
      }
    }
    __syncthreads();
#pragma unroll
    for (int i = 0; i < 4; ++i) {
      const int u = t + i * 256;
      const int kc = u >> 6;
      const int l = u & 63;
      const f16x8 pack = *(const f16x8*)&tile[l & 31][kc * 16 + ((l >> 5) & 1) * 8];
      *(f16x8*)(kfrag + (size_t)c * 8192 + (size_t)u * 8) = pack;
    }
#pragma unroll
    for (int i = 0; i < 4; ++i) {
      const int u = t + i * 256;
      const int fi = u >> 6;
      const int l = u & 63;
      const int dt = fi >> 1, ks = fi & 1;
      f16x8 pack;
#pragma unroll
      for (int j = 0; j < 8; ++j)
        pack[j] = tile[ks * 16 + ((l >> 5) & 1) * 8 + j][dt * 32 + (l & 31)];
      *(f16x8*)(vfrag + (size_t)c * 8192 + (size_t)u * 8) = pack;
    }
  } else {
    __shared__ float ftile[32][257];
    const int c = bid - 256;
    {
      const int r = t >> 3;
      const int d0 = (t & 7) * 32;
      const float4* src = (const float4*)(embd + (size_t)(c * 32 + r) * 256 + d0);
#pragma unroll
      for (int q8 = 0; q8 < 8; ++q8) {
        const float4 v = src[q8];
        ftile[r][d0 + q8 * 4 + 0] = v.x;
        ftile[r][d0 + q8 * 4 + 1] = v.y;
        ftile[r][d0 + q8 * 4 + 2] = v.z;
        ftile[r][d0 + q8 * 4 + 3] = v.w;
      }
    }
    __syncthreads();
    const int r = t & 31;
    const int dh = t >> 5;
#pragma unroll
    for (int dd = 0; dd < 32; ++dd) {
      const int d = dd * 8 + dh;
      embd_t[(size_t)d * 8192 + c * 32 + r] = ftile[r][d];
    }
  }
}

// ---------------- fused: LN + flash softmax-quantize (UNCHANGED from R13) ----------
__global__ __launch_bounds__(256, 2) void fused_kernel(
    const float* __restrict__ input, const float* __restrict__ ln_w,
    const float* __restrict__ ln_b, const f16* __restrict__ kfrag,
    const f16* __restrict__ vfrag, float* __restrict__ out_q,
    float* __restrict__ out_idx, unsigned* __restrict__ count,
    int* __restrict__ list) {
  __shared__ __align__(16) char lds[36864];
  const int tid = threadIdx.x;
  const int lane = tid & 63;
  const int w = tid >> 6;  // nq quarter
  const int q = lane & 31;
  const int hi = lane >> 5;
  const int R0 = blockIdx.x * 32;

  const f16* const kfbase = kfrag + (size_t)(w * 64) * 8192 + (size_t)lane * 8;
  const f16* const vfbase = vfrag + (size_t)(w * 64) * 8192 + (size_t)lane * 8;
  const char* const qb = lds + hi * 512 + q * 16;

  f16x8 kA[8];
#pragma unroll
  for (int f = 0; f < 8; ++f) kA[f] = *(const f16x8*)(kfbase + f * 512);

  {
    const int r = tid >> 3;
    const int seg = tid & 7;
    const float* rowp = input + (size_t)(R0 + r) * 256 + seg * 32;
    float4 xv[8];
    float sm = 0.f, ssq = 0.f;
#pragma unroll
    for (int qd = 0; qd < 8; ++qd) {
      xv[qd] = ((const float4*)rowp)[qd];
      sm += xv[qd].x + xv[qd].y + xv[qd].z + xv[qd].w;
      ssq += xv[qd].x * xv[qd].x + xv[qd].y * xv[qd].y + xv[qd].z * xv[qd].z +
             xv[qd].w * xv[qd].w;
    }
    sm += __shfl_xor(sm, 1);
    sm += __shfl_xor(sm, 2);
    sm += __shfl_xor(sm, 4);
    ssq += __shfl_xor(ssq, 1);
    ssq += __shfl_xor(ssq, 2);
    ssq += __shfl_xor(ssq, 4);
    const float mean = sm * (1.f / 256.f);
    const float var = ssq * (1.f / 256.f) - mean * mean;
    const float rstd = 1.0f / sqrtf(var + LN_EPS);
#pragma unroll
    for (int qd = 0; qd < 8; ++qd) {
      const int d0 = seg * 32 + qd * 4;
      float4 w4 = *(const float4*)(ln_w + d0);
      float4 b4 = *(const float4*)(ln_b + d0);
      f16x4 hv;
      hv[0] = (f16)((((xv[qd].x - mean) * rstd) * w4.x + b4.x) * SCL);
      hv[1] = (f16)((((xv[qd].y - mean) * rstd) * w4.y + b4.y) * SCL);
      hv[2] = (f16)((((xv[qd].z - mean) * rstd) * w4.z + b4.z) * SCL);
      hv[3] = (f16)((((xv[qd].w - mean) * rstd) * w4.w + b4.w) * SCL);
      const int off = (d0 >> 4) * 1024 + ((d0 >> 3) & 1) * 512 + r * 16 + (d0 & 7) * 2;
      *(f16x4*)(lds + off) = hv;
    }
  }
  __syncthreads();

  f32x16 acc[8] = {};
  float m_run = 0.f, l_run = 0.f, mt1 = -3.0e38f, mt2 = -3.0e38f;
  int i1 = 0;

  for (int c = 0; c < 64; ++c) {
    const int nb = w * 2048 + c * 32;
    const f16* const kc_base = kfbase + (size_t)c * 8192;
    const f16* const vc_base = vfbase + (size_t)c * 8192;
    SBAR();
    __builtin_amdgcn_s_barrier();
    SBAR();
    f16x8 kB[8];
#pragma unroll
    for (int f = 0; f < 8; ++f) kB[f] = *(const f16x8*)(kc_base + 4096 + f * 512);
    f32x16 S = {};
#pragma unroll
    for (int kc = 0; kc < 8; ++kc) {
      const f16x8 qf = *(const f16x8*)(qb + kc * 1024);
      S = MFMA32(kA[kc], qf, S);
    }
    f16x8 va[8];
#pragma unroll
    for (int dt = 0; dt < 8; ++dt) va[dt] = *(const f16x8*)(vc_base + dt * 1024);
#pragma unroll
    for (int kc = 0; kc < 8; ++kc) {
      const f16x8 qf = *(const f16x8*)(qb + (8 + kc) * 1024);
      S = MFMA32(kB[kc], qf, S);
    }
    f16x8 vb[8];
#pragma unroll
    for (int dt = 0; dt < 8; ++dt)
      vb[dt] = *(const f16x8*)(vc_base + 512 + dt * 1024);

    const float y0 = fmaxf(fmaxf(S[0], S[1]), fmaxf(S[2], S[3]));
    const float y1 = fmaxf(fmaxf(S[4], S[5]), fmaxf(S[6], S[7]));
    const float y2 = fmaxf(fmaxf(S[8], S[9]), fmaxf(S[10], S[11]));
    const float y3 = fmaxf(fmaxf(S[12], S[13]), fmaxf(S[14], S[15]));
    const float t1h = fmaxf(fmaxf(y0, y1), fmaxf(y2, y3));
    const float o1 = __shfl_xor(t1h, 32);
    const float t1max = fmaxf(t1h, o1);
    if (__any(t1max - m_run > 8.f)) {
      const float mnew = fmaxf(m_run, t1max);
      const float a = exp2f(m_run - mnew);
      l_run *= a;
      m_run = mnew;
      float av[16];
#pragma unroll
      for (int r = 0; r < 16; ++r)
        av[r] = __shfl(a, (r & 3) + 8 * (r >> 2) + hi * 4);
#pragma unroll
      for (int dt = 0; dt < 8; ++dt)
#pragma unroll
        for (int r = 0; r < 16; ++r) acc[dt][r] *= av[r];
    }
    float P[16];
#pragma unroll
    for (int r = 0; r < 16; ++r) P[r] = exp2f(S[r] - m_run);
    l_run += ((((P[0] + P[1]) + (P[2] + P[3])) + ((P[4] + P[5]) + (P[6] + P[7]))) +
              (((P[8] + P[9]) + (P[10] + P[11])) + ((P[12] + P[13]) + (P[14] + P[15]))));
    unsigned cc[8], xx[8];
#pragma unroll
    for (int i2 = 0; i2 < 8; ++i2) {
      auto pk = __builtin_amdgcn_cvt_pkrtz(P[2 * i2], P[2 * i2 + 1]);
      cc[i2] = __builtin_bit_cast(unsigned, pk);
    }
#pragma unroll
    for (int i2 = 0; i2 < 8; ++i2)
      xx[i2] = (unsigned)__shfl_xor((int)cc[i2], 32);
    uint32x4 u0, u1;
    u0[0] = hi ? xx[2] : cc[0];
    u0[1] = hi ? xx[3] : cc[1];
    u0[2] = hi ? cc[2] : xx[0];
    u0[3] = hi ? cc[3] : xx[1];
    u1[0] = hi ? xx[6] : cc[4];
    u1[1] = hi ? xx[7] : cc[5];
    u1[2] = hi ? cc[6] : xx[4];
    u1[3] = hi ? cc[7] : xx[5];
    const f16x8 pa0 = __builtin_bit_cast(f16x8, u0);
    const f16x8 pa1 = __builtin_bit_cast(f16x8, u1);

#pragma unroll
    for (int dt = 0; dt < 8; ++dt) acc[dt] = MFMA32(pa0, va[dt], acc[dt]);
    {
      const f16* p = kfbase + (size_t)((c + 1) & 63) * 8192;
#pragma unroll
      for (int f = 0; f < 8; ++f) kA[f] = *(const f16x8*)(p + f * 512);
    }
#pragma unroll
    for (int dt = 0; dt < 8; ++dt) acc[dt] = MFMA32(pa1, vb[dt], acc[dt]);

    {
      const int nbh = nb + hi * 4;
      int lih = 27;
#pragma unroll
      for (int r = 14; r >= 0; --r) {
        const int rl = (r & 3) + 8 * (r >> 2);
        lih = (S[r] == t1h) ? rl : lih;
      }
      float t2h = -3.0e38f;
#pragma unroll
      for (int r = 0; r < 16; ++r) {
        const int rl = (r & 3) + 8 * (r >> 2);
        t2h = fmaxf(t2h, (lih == rl) ? -3.0e38f : S[r]);
      }
      const int ti_h = nbh + lih;
      const float o2 = __shfl_xor(t2h, 32);
      const int oi = __shfl_xor(ti_h, 32);
      float t1, t2;
      int ti;
      if (o1 > t1h || (o1 == t1h && oi < ti_h)) {
        t1 = o1; ti = oi; t2 = fmaxf(t1h, o2);
      } else {
        t1 = t1h; ti = ti_h; t2 = fmaxf(t2h, o1);
      }
      if (t1 > mt1) { mt2 = fmaxf(mt1, t2); mt1 = t1; i1 = ti; }
      else { mt2 = fmaxf(mt2, t1); }
    }
  }

  __syncthreads();
  const float lf = l_run + __shfl_xor(l_run, 32);
  float4* statA = (float4*)(lds + 32768);
  int* statB = (int*)(lds + 32768 + 2048);
  if (hi == 0) {
    statA[w * 32 + q] = make_float4(m_run, lf, mt1, mt2);
    statB[w * 32 + q] = i1;
  }
  __syncthreads();
  const float4 s0 = statA[0 * 32 + q];
  const float4 s1 = statA[1 * 32 + q];
  const float4 s2 = statA[2 * 32 + q];
  const float4 s3 = statA[3 * 32 + q];
  const float mstar = fmaxf(fmaxf(s0.x, s1.x), fmaxf(s2.x, s3.x));
  const float lstar = s0.y * exp2f(s0.x - mstar) + s1.y * exp2f(s1.x - mstar) +
                      s2.y * exp2f(s2.x - mstar) + s3.y * exp2f(s3.x - mstar);
  const float a_self = exp2f(m_run - mstar);
  const float inv = 1.0f / lstar;
  if (w == 0 && hi == 0) {
    float wm = s0.z, wm2 = s0.w;
    int wi = statB[q];
    if (s1.z > wm) { wm2 = fmaxf(wm, s1.w); wm = s1.z; wi = statB[32 + q]; }
    else wm2 = fmaxf(wm2, s1.z);
    if (s2.z > wm) { wm2 = fmaxf(wm, s2.w); wm = s2.z; wi = statB[64 + q]; }
    else wm2 = fmaxf(wm2, s2.z);
    if (s3.z > wm) { wm2 = fmaxf(wm, s3.w); wm = s3.z; wi = statB[96 + q]; }
    else wm2 = fmaxf(wm2, s3.z);
    const int row = R0 + q;
    out_idx[row] = (float)wi;
    if (wm - wm2 <= DELTA) {
      const unsigned pos = atomicAdd(count, 1u);
      list[pos] = row;
    }
  }
  float av[16], ivr[16];
#pragma unroll
  for (int r = 0; r < 16; ++r) {
    const int qr = (r & 3) + 8 * (r >> 2) + hi * 4;
    av[r] = __shfl(a_self, qr);
    ivr[r] = __shfl(inv, qr);
  }
#pragma unroll
  for (int dt = 0; dt < 8; ++dt)
#pragma unroll
    for (int r = 0; r < 16; ++r) acc[dt][r] *= av[r];
  __syncthreads();
  float* region = (float*)lds;
#define MRG_ADDR(dt, r) (((r & 3) + 8 * (r >> 2) + hi * 4) * 256 + dt * 32 + q)
  if (w == 1) {
#pragma unroll
    for (int dt = 0; dt < 8; ++dt)
#pragma unroll
      for (int r = 0; r < 16; ++r) region[MRG_ADDR(dt, r)] = acc[dt][r];
  }
  __syncthreads();
  if (w == 0) {
#pragma unroll
    for (int dt = 0; dt < 8; ++dt)
#pragma unroll
      for (int r = 0; r < 16; ++r) acc[dt][r] += region[MRG_ADDR(dt, r)];
  }
  __syncthreads();
  if (w == 3) {
#pragma unroll
    for (int dt = 0; dt < 8; ++dt)
#pragma unroll
      for (int r = 0; r < 16; ++r) region[MRG_ADDR(dt, r)] = acc[dt][r];
  }
  __syncthreads();
  if (w == 2) {
#pragma unroll
    for (int dt = 0; dt < 8; ++dt)
#pragma unroll
      for (int r = 0; r < 16; ++r) acc[dt][r] += region[MRG_ADDR(dt, r)];
  }
  __syncthreads();
  if (w == 2) {
#pragma unroll
    for (int dt = 0; dt < 8; ++dt)
#pragma unroll
      for (int r = 0; r < 16; ++r) region[MRG_ADDR(dt, r)] = acc[dt][r];
  }
  __syncthreads();
  if (w == 0) {
#pragma unroll
    for (int dt = 0; dt < 8; ++dt)
#pragma unroll
      for (int r = 0; r < 16; ++r) {
        const int qr = (r & 3) + 8 * (r >> 2) + hi * 4;
        const float v = (acc[dt][r] + region[MRG_ADDR(dt, r)]) * ivr[r];
        out_q[(size_t)(R0 + qr) * 256 + dt * 32 + q] = v;
      }
  }
#undef MRG_ADDR
}

// ---------------- refine_part: exact fp32 argmax partials, 8 rows x 8 n-slices ----
// task = (row-group of 8, slice of 1024 n). 8-row batching halves embd_t traffic.
__global__ __launch_bounds__(256) void refine_part_kernel(
    const float* __restrict__ input, const float* __restrict__ ln_w,
    const float* __restrict__ ln_b, const float* __restrict__ embd_t,
    const unsigned* __restrict__ count, const int* __restrict__ list,
    float2* __restrict__ part) {
  __shared__ float xr[8][256];
  __shared__ float redv[4][8];
  __shared__ int redn[4][8];
  const int tid = threadIdx.x;
  const unsigned cnt = *count;
  if (cnt == 0) return;
  const unsigned ntask = ((cnt + 7u) >> 3) * 8u;
  for (unsigned task = blockIdx.x; task < ntask; task += gridDim.x) {
    const unsigned grp = task >> 3;
    const int slice = (int)(task & 7u);
    __syncthreads();  // reuse guard across grid-stride iterations
    {
      // 8 rows LN'd in parallel: 32-lane group per row
      const int rr = tid >> 5;
      const int sl = tid & 31;
      unsigned ridx = grp * 8u + (unsigned)rr;
      if (ridx >= cnt) ridx = cnt - 1u;
      const int row = list[ridx];
      const float* rp = input + (size_t)row * 256 + sl * 8;
      const float4 a = ((const float4*)rp)[0];
      const float4 b = ((const float4*)rp)[1];
      float sm = a.x + a.y + a.z + a.w + b.x + b.y + b.z + b.w;
      float ssq = a.x * a.x + a.y * a.y + a.z * a.z + a.w * a.w +
                  b.x * b.x + b.y * b.y + b.z * b.z + b.w * b.w;
#pragma unroll
      for (int mk = 1; mk <= 16; mk <<= 1) {
        sm += __shfl_xor(sm, mk);
        ssq += __shfl_xor(ssq, mk);
      }
      const float mean = sm * (1.f / 256.f);
      const float var = ssq * (1.f / 256.f) - mean * mean;
      const float rstd = 1.0f / sqrtf(var + LN_EPS);
      const float4 w0 = ((const float4*)(ln_w + sl * 8))[0];
      const float4 w1 = ((const float4*)(ln_w + sl * 8))[1];
      const float4 b0 = ((const float4*)(ln_b + sl * 8))[0];
      const float4 b1 = ((const float4*)(ln_b + sl * 8))[1];
      float4 o0, o1;
      o0.x = (a.x - mean) * rstd * w0.x + b0.x;
      o0.y = (a.y - mean) * rstd * w0.y + b0.y;
      o0.z = (a.z - mean) * rstd * w0.z + b0.z;
      o0.w = (a.w - mean) * rstd * w0.w + b0.w;
      o1.x = (b.x - mean) * rstd * w1.x + b1.x;
      o1.y = (b.y - mean) * rstd * w1.y + b1.y;
      o1.z = (b.z - mean) * rstd * w1.z + b1.z;
      o1.w = (b.w - mean) * rstd * w1.w + b1.w;
      *(float4*)&xr[rr][sl * 8] = o0;
      *(float4*)&xr[rr][sl * 8 + 4] = o1;
    }
    __syncthreads();
    // scan 1024 n: thread owns n0, n0+256, n0+512, n0+768 (lane-consecutive)
    const int n0 = slice * 1024 + tid;
    float dv[4][8] = {};  // [k][rr]
#pragma unroll 2
    for (int dq = 0; dq < 64; ++dq) {
      float4 x[8];
#pragma unroll
      for (int rr = 0; rr < 8; ++rr) x[rr] = *(const float4*)&xr[rr][dq * 4];
      const float* e0 = embd_t + (size_t)(dq * 4 + 0) * 8192 + n0;
      const float* e1 = embd_t + (size_t)(dq * 4 + 1) * 8192 + n0;
      const float* e2 = embd_t + (size_t)(dq * 4 + 2) * 8192 + n0;
      const float* e3 = embd_t + (size_t)(dq * 4 + 3) * 8192 + n0;
#pragma unroll
      for (int k = 0; k < 4; ++k) {
        const float ea = e0[k * 256];
        const float eb = e1[k * 256];
        const float ec = e2[k * 256];
        const float ed = e3[k * 256];
#pragma unroll
        for (int rr = 0; rr < 8; ++rr)
          dv[k][rr] += x[rr].x * ea + x[rr].y * eb + x[rr].z * ec + x[rr].w * ed;
      }
    }
#pragma unroll
    for (int rr = 0; rr < 8; ++rr) {
      float v = dv[0][rr];
      int nn = n0;
#pragma unroll
      for (int k = 1; k < 4; ++k)
        if (dv[k][rr] > v) { v = dv[k][rr]; nn = n0 + k * 256; }
#pragma unroll
      for (int mk = 1; mk <= 32; mk <<= 1) {
        const float ov = __shfl_xor(v, mk);
        const int on = __shfl_xor(nn, mk);
        if (ov > v || (ov == v && on < nn)) { v = ov; nn = on; }
      }
      if ((tid & 63) == 0) {
        redv[tid >> 6][rr] = v;
        redn[tid >> 6][rr] = nn;
      }
    }
    __syncthreads();
    if (tid < 8) {
      const unsigned ridx = grp * 8u + (unsigned)tid;
      if (ridx < cnt) {
        float v = redv[0][tid];
        int nn = redn[0][tid];
#pragma unroll
        for (int wv = 1; wv < 4; ++wv) {
          const float ov = redv[wv][tid];
          const int on = redn[wv][tid];
          if (ov > v || (ov == v && on < nn)) { v = ov; nn = on; }
        }
        part[ridx * 8u + (unsigned)slice] = make_float2(v, (float)nn);
      }
    }
  }
}

// ---------------- refine_merge: fold 8 slice partials per flagged row ----------------
__global__ __launch_bounds__(256) void refine_merge_kernel(
    float* __restrict__ out_idx, const unsigned* __restrict__ count,
    const int* __restrict__ list, const float2* __restrict__ part) {
  const unsigned cnt = *count;
  for (unsigned i = blockIdx.x * 256u + threadIdx.x; i < cnt;
       i += gridDim.x * 256u) {
    float v = -3.0e38f;
    int nn = 0;
#pragma unroll
    for (int s = 0; s < 8; ++s) {
      const float2 p = part[i * 8u + (unsigned)s];
      const int on = (int)p.y;
      if (p.x > v || (p.x == v && on < nn)) { v = p.x; nn = on; }
    }
    out_idx[list[i]] = (float)nn;
  }
}

extern "C" void kernel_launch(void* const* d_in, const int* in_sizes, int n_in,
                              void* d_out, int out_size, void* d_ws,
                              size_t ws_size, hipStream_t stream) {
  (void)in_sizes;
  (void)n_in;
  (void)out_size;
  (void)ws_size;
  const float* input = (const float*)d_in[0];
  const float* ln_w = (const float*)d_in[1];
  const float* ln_b = (const float*)d_in[2];
  const float* embd = (const float*)d_in[3];
  float* out_q = (float*)d_out;
  float* out_idx = out_q + (size_t)M_TOT * 256;
  char* ws = (char*)d_ws;
  f16* kfrag = (f16*)(ws + WS_KFRAG);
  f16* vfrag = (f16*)(ws + WS_VFRAG);
  unsigned* count = (unsigned*)(ws + WS_COUNT);
  int* list = (int*)(ws + WS_LIST);
  float2* part = (float2*)(ws + WS_PART);
  float* embd_t = (float*)(ws + WS_EMBDT);

  prep_kernel<<<512, 256, 0, stream>>>(embd, kfrag, vfrag, embd_t, count);
  fused_kernel<<<512, 256, 0, stream>>>(input, ln_w, ln_b, kfrag, vfrag,
                                        out_q, out_idx, count, list);
  refine_part_kernel<<<256, 256, 0, stream>>>(input, ln_w, ln_b, embd_t,
                                              count, list, part);
  refine_merge_kernel<<<16, 256, 0, stream>>>(out_idx, count, list, part);
}